// Round 1
// baseline (2191.323 us; speedup 1.0000x reference)
//
#include <hip/hip_runtime.h>
#include <math.h>

#define BB 2
#define SS 2048
#define DIMM 1024
#define HH 16
#define DD 64
#define WINDOW 512

// ------------------------------------------------------------------
// Kernel 1: mix & gate  (sigmoid(tokens @ Wg), sigmoid(tokens @ Wmix))
// one block per (b,s); 256 threads; 32 outputs (16 gate + 16 mix)
// ------------------------------------------------------------------
__global__ __launch_bounds__(256) void mixgate_kernel(
    const float* __restrict__ tokens, const float* __restrict__ Wg,
    const float* __restrict__ Wmix, float* __restrict__ gate,
    float* __restrict__ mix)
{
    int m = blockIdx.x;            // b*S + s
    int b = m >> 11, s = m & 2047;
    int tid = threadIdx.x;
    __shared__ float tok[1024];
    const float4* t4 = (const float4*)(tokens + (size_t)m * DIMM);
    ((float4*)tok)[tid] = t4[tid];           // 256 * 4 = 1024 floats
    __syncthreads();

    int out  = tid >> 3;    // 0..31
    int part = tid & 7;     // 0..7
    int h    = out & 15;
    const float* W = (out < 16) ? Wg : Wmix;
    float acc = 0.f;
    int k0 = part * 128;
    #pragma unroll 4
    for (int kk = k0; kk < k0 + 128; ++kk)
        acc += tok[kk] * W[kk * HH + h];
    acc += __shfl_down(acc, 4, 8);
    acc += __shfl_down(acc, 2, 8);
    acc += __shfl_down(acc, 1, 8);
    if (part == 0) {
        float sg = 1.f / (1.f + __expf(-acc));
        float* dst = (out < 16) ? gate : mix;
        dst[((size_t)b * HH + h) * SS + s] = sg;
    }
}

// ------------------------------------------------------------------
// Kernel 2: projection GEMM  tokens(4096x1024) @ [Wq|Wkv](1024x3072)
// scatter epilogue into q/k/v buffers laid out (B,H,S,D)
// BM=BN=64, BK=16, 256 threads, 4x4 microtile
// ------------------------------------------------------------------
__global__ __launch_bounds__(256) void gemm_proj(
    const float* __restrict__ A, const float* __restrict__ Wq,
    const float* __restrict__ Wkv, float* __restrict__ qb,
    float* __restrict__ kb, float* __restrict__ vb)
{
    const int K = 1024;
    int colBase = blockIdx.x * 64;   // 0..3008
    int rowBase = blockIdx.y * 64;   // 0..4032
    int tid = threadIdx.x;

    __shared__ float As[16][64];
    __shared__ float Bs[16][68];

    int a_row = tid >> 2;            // 0..63
    int a_kc  = (tid & 3) * 4;       // 0,4,8,12
    int b_kr  = tid >> 4;            // 0..15
    int b_nc  = (tid & 15) * 4;      // 0..60

    int tm = (tid >> 4) * 4;         // 0..60
    int tn = (tid & 15) * 4;         // 0..60

    float acc[4][4];
    #pragma unroll
    for (int i = 0; i < 4; ++i)
        #pragma unroll
        for (int j = 0; j < 4; ++j) acc[i][j] = 0.f;

    for (int k0 = 0; k0 < K; k0 += 16) {
        // load A tile
        float4 av = *(const float4*)(A + (size_t)(rowBase + a_row) * K + k0 + a_kc);
        // load B tile (concat of Wq and Wkv columns)
        int c = colBase + b_nc;
        const float* bp;
        if (c < 1024) bp = Wq  + (size_t)(k0 + b_kr) * 1024 + c;
        else          bp = Wkv + (size_t)(k0 + b_kr) * 2048 + (c - 1024);
        float4 bv = *(const float4*)bp;

        As[a_kc + 0][a_row] = av.x;
        As[a_kc + 1][a_row] = av.y;
        As[a_kc + 2][a_row] = av.z;
        As[a_kc + 3][a_row] = av.w;
        *(float4*)&Bs[b_kr][b_nc] = bv;
        __syncthreads();

        #pragma unroll
        for (int kk = 0; kk < 16; ++kk) {
            float4 a4 = *(const float4*)&As[kk][tm];
            float4 b4 = *(const float4*)&Bs[kk][tn];
            float avv[4] = {a4.x, a4.y, a4.z, a4.w};
            float bvv[4] = {b4.x, b4.y, b4.z, b4.w};
            #pragma unroll
            for (int i = 0; i < 4; ++i)
                #pragma unroll
                for (int j = 0; j < 4; ++j)
                    acc[i][j] = fmaf(avv[i], bvv[j], acc[i][j]);
        }
        __syncthreads();
    }

    // scatter epilogue
    #pragma unroll
    for (int i = 0; i < 4; ++i) {
        int m = rowBase + tm + i;
        int b = m >> 11, s = m & 2047;
        #pragma unroll
        for (int j = 0; j < 4; ++j) {
            int c = colBase + tn + j;
            int cc = c & 1023;
            int h = cc >> 6, d = cc & 63;
            size_t o = (((size_t)b * HH + h) * SS + s) * DD + d;
            float* dst = (c < 1024) ? qb : (c < 2048) ? kb : vb;
            dst[o] = acc[i][j];
        }
    }
}

// ------------------------------------------------------------------
// Kernel 3: RoPE on q (with scale) and k; lerp v with value_residual
// one block (64 threads) per (b,h,s)
// ------------------------------------------------------------------
__global__ __launch_bounds__(64) void rope_lerp_kernel(
    float* __restrict__ q, float* __restrict__ k, float* __restrict__ v,
    const float* __restrict__ vr, const float* __restrict__ mix)
{
    int idx = blockIdx.x;           // (b*H + h)*S + s
    int s = idx & 2047;
    int d = threadIdx.x;
    size_t off = (size_t)idx * DD + d;

    int m2 = (d >> 1) * 2;
    float inv_freq = powf(10000.f, -(float)m2 * (1.f / 64.f));
    float fr = (float)s * inv_freq;
    float cs, sn;
    sincosf(fr, &sn, &cs);

    float qv = q[off] * 0.125f;     // scale = D^-0.5
    float qp = __shfl_xor(qv, 1);
    float qr = (d & 1) ? qp : -qp;
    q[off] = qv * cs + qr * sn;

    float kv = k[off];
    float kp = __shfl_xor(kv, 1);
    float kr = (d & 1) ? kp : -kp;
    k[off] = kv * cs + kr * sn;

    float vv = v[off];
    float mxv = mix[idx];
    v[off] = vv + mxv * (vr[off] - vv);
}

// ------------------------------------------------------------------
// Kernel 4: sliding-window attention, one block per (b,h,i)
// ------------------------------------------------------------------
__global__ __launch_bounds__(256) void attn_kernel(
    const float* __restrict__ q, const float* __restrict__ kbuf,
    const float* __restrict__ vbuf, const int* __restrict__ ep,
    const float* __restrict__ gate, float* __restrict__ ao)
{
    int idx = blockIdx.x;
    int i  = idx & (SS - 1);
    int bh = idx >> 11;
    int h  = bh & (HH - 1);
    int b  = bh >> 4;
    int tid = threadIdx.x;

    __shared__ float qs[64];
    __shared__ float sc[520];
    __shared__ float red[256];
    __shared__ float part[256];

    const float* qrow = q + ((size_t)bh * SS + i) * DD;
    if (tid < 64) qs[tid] = qrow[tid];
    int epi = ep[b * SS + i];
    int jlo = i - WINDOW; if (jlo < 0) jlo = 0;
    int nj = i - jlo + 1;            // <= 513
    __syncthreads();

    // scores
    for (int t = tid; t < nj; t += 256) {
        int j = jlo + t;
        const float4* k4 = (const float4*)(kbuf + ((size_t)bh * SS + j) * DD);
        const float4* q4 = (const float4*)qs;
        float acc = 0.f;
        #pragma unroll
        for (int u = 0; u < 16; ++u) {
            float4 kk = k4[u]; float4 qq = q4[u];
            acc += qq.x * kk.x + qq.y * kk.y + qq.z * kk.z + qq.w * kk.w;
        }
        sc[t] = (ep[b * SS + j] == epi) ? acc : -1e30f;
    }
    __syncthreads();

    // max
    float lm = -1e30f;
    for (int t = tid; t < nj; t += 256) lm = fmaxf(lm, sc[t]);
    red[tid] = lm; __syncthreads();
    for (int off = 128; off > 0; off >>= 1) {
        if (tid < off) red[tid] = fmaxf(red[tid], red[tid + off]);
        __syncthreads();
    }
    float mx = red[0];
    __syncthreads();

    // exp + sum
    float ls = 0.f;
    for (int t = tid; t < nj; t += 256) {
        float e = __expf(sc[t] - mx);
        sc[t] = e;
        ls += e;
    }
    red[tid] = ls; __syncthreads();
    for (int off = 128; off > 0; off >>= 1) {
        if (tid < off) red[tid] += red[tid + off];
        __syncthreads();
    }
    float inv = 1.f / red[0];

    // PV
    int d = tid & 63, p = tid >> 6;
    float acc = 0.f;
    for (int t = p; t < nj; t += 4) {
        const float* vrow = vbuf + ((size_t)bh * SS + jlo + t) * DD;
        acc = fmaf(sc[t], vrow[d], acc);
    }
    part[tid] = acc; __syncthreads();
    if (p == 0) {
        float o = (part[d] + part[64 + d] + part[128 + d] + part[192 + d]) * inv;
        float g = gate[(size_t)bh * SS + i];
        ao[(((size_t)b * SS + i) * HH + h) * DD + d] = o * g;
    }
}

// ------------------------------------------------------------------
// Kernel 5: output GEMM  ao(4096x1024) @ Wo(1024x1024) -> out
// ------------------------------------------------------------------
__global__ __launch_bounds__(256) void gemm_out(
    const float* __restrict__ A, const float* __restrict__ Bm,
    float* __restrict__ C)
{
    const int K = 1024, N = 1024;
    int colBase = blockIdx.x * 64;
    int rowBase = blockIdx.y * 64;
    int tid = threadIdx.x;

    __shared__ float As[16][64];
    __shared__ float Bs[16][68];

    int a_row = tid >> 2;
    int a_kc  = (tid & 3) * 4;
    int b_kr  = tid >> 4;
    int b_nc  = (tid & 15) * 4;
    int tm = (tid >> 4) * 4;
    int tn = (tid & 15) * 4;

    float acc[4][4];
    #pragma unroll
    for (int i = 0; i < 4; ++i)
        #pragma unroll
        for (int j = 0; j < 4; ++j) acc[i][j] = 0.f;

    for (int k0 = 0; k0 < K; k0 += 16) {
        float4 av = *(const float4*)(A + (size_t)(rowBase + a_row) * K + k0 + a_kc);
        float4 bv = *(const float4*)(Bm + (size_t)(k0 + b_kr) * N + colBase + b_nc);
        As[a_kc + 0][a_row] = av.x;
        As[a_kc + 1][a_row] = av.y;
        As[a_kc + 2][a_row] = av.z;
        As[a_kc + 3][a_row] = av.w;
        *(float4*)&Bs[b_kr][b_nc] = bv;
        __syncthreads();

        #pragma unroll
        for (int kk = 0; kk < 16; ++kk) {
            float4 a4 = *(const float4*)&As[kk][tm];
            float4 b4 = *(const float4*)&Bs[kk][tn];
            float avv[4] = {a4.x, a4.y, a4.z, a4.w};
            float bvv[4] = {b4.x, b4.y, b4.z, b4.w};
            #pragma unroll
            for (int i = 0; i < 4; ++i)
                #pragma unroll
                for (int j = 0; j < 4; ++j)
                    acc[i][j] = fmaf(avv[i], bvv[j], acc[i][j]);
        }
        __syncthreads();
    }

    #pragma unroll
    for (int i = 0; i < 4; ++i) {
        float* crow = C + (size_t)(rowBase + tm + i) * N + colBase + tn;
        #pragma unroll
        for (int j = 0; j < 4; ++j) crow[j] = acc[i][j];
    }
}

// ------------------------------------------------------------------
extern "C" void kernel_launch(void* const* d_in, const int* in_sizes, int n_in,
                              void* d_out, int out_size, void* d_ws, size_t ws_size,
                              hipStream_t stream)
{
    const float* tokens = (const float*)d_in[0];
    const float* vres   = (const float*)d_in[1];
    const int*   ep     = (const int*)d_in[2];
    const float* Wq     = (const float*)d_in[3];
    const float* Wkv    = (const float*)d_in[4];
    const float* Wo     = (const float*)d_in[5];
    const float* Wg     = (const float*)d_in[6];
    const float* Wmix   = (const float*)d_in[7];
    float* out = (float*)d_out;

    const size_t BHSD = (size_t)BB * HH * SS * DD;   // 4,194,304
    float* ws   = (float*)d_ws;
    float* qb   = ws;
    float* kb   = qb + BHSD;
    float* vb   = kb + BHSD;
    float* ao   = vb + BHSD;
    float* gatep = ao + BHSD;
    float* mixp  = gatep + (size_t)BB * HH * SS;

    mixgate_kernel<<<BB * SS, 256, 0, stream>>>(tokens, Wg, Wmix, gatep, mixp);
    gemm_proj<<<dim3(48, 64), 256, 0, stream>>>(tokens, Wq, Wkv, qb, kb, vb);
    rope_lerp_kernel<<<BB * HH * SS, 64, 0, stream>>>(qb, kb, vb, vres, mixp);
    attn_kernel<<<BB * HH * SS, 256, 0, stream>>>(qb, kb, vb, ep, gatep, ao);
    gemm_out<<<dim3(16, 64), 256, 0, stream>>>(ao, Wo, out);
}

// Round 2
// 771.613 us; speedup vs baseline: 2.8399x; 2.8399x over previous
//
#include <hip/hip_runtime.h>
#include <math.h>

#define BB 2
#define SS 2048
#define DIMM 1024
#define HH 16
#define DD 64
#define WINDOW 512

// ------------------------------------------------------------------
// Kernel 1: mix & gate  (sigmoid(tokens @ Wg), sigmoid(tokens @ Wmix))
// ------------------------------------------------------------------
__global__ __launch_bounds__(256) void mixgate_kernel(
    const float* __restrict__ tokens, const float* __restrict__ Wg,
    const float* __restrict__ Wmix, float* __restrict__ gate,
    float* __restrict__ mix)
{
    int m = blockIdx.x;            // b*S + s
    int b = m >> 11, s = m & 2047;
    int tid = threadIdx.x;
    __shared__ float tok[1024];
    const float4* t4 = (const float4*)(tokens + (size_t)m * DIMM);
    ((float4*)tok)[tid] = t4[tid];
    __syncthreads();

    int out  = tid >> 3;    // 0..31
    int part = tid & 7;     // 0..7
    int h    = out & 15;
    const float* W = (out < 16) ? Wg : Wmix;
    float acc = 0.f;
    int k0 = part * 128;
    #pragma unroll 4
    for (int kk = k0; kk < k0 + 128; ++kk)
        acc += tok[kk] * W[kk * HH + h];
    acc += __shfl_down(acc, 4, 8);
    acc += __shfl_down(acc, 2, 8);
    acc += __shfl_down(acc, 1, 8);
    if (part == 0) {
        float sg = 1.f / (1.f + __expf(-acc));
        float* dst = (out < 16) ? gate : mix;
        dst[((size_t)b * HH + h) * SS + s] = sg;
    }
}

// ------------------------------------------------------------------
// Kernel 2: projection GEMM  tokens(4096x1024) @ [Wq|Wkv](1024x3072)
// ------------------------------------------------------------------
__global__ __launch_bounds__(256) void gemm_proj(
    const float* __restrict__ A, const float* __restrict__ Wq,
    const float* __restrict__ Wkv, float* __restrict__ qb,
    float* __restrict__ kb, float* __restrict__ vb)
{
    const int K = 1024;
    int colBase = blockIdx.x * 64;
    int rowBase = blockIdx.y * 64;
    int tid = threadIdx.x;

    __shared__ float As[16][64];
    __shared__ float Bs[16][68];

    int a_row = tid >> 2;
    int a_kc  = (tid & 3) * 4;
    int b_kr  = tid >> 4;
    int b_nc  = (tid & 15) * 4;
    int tm = (tid >> 4) * 4;
    int tn = (tid & 15) * 4;

    float acc[4][4];
    #pragma unroll
    for (int i = 0; i < 4; ++i)
        #pragma unroll
        for (int j = 0; j < 4; ++j) acc[i][j] = 0.f;

    for (int k0 = 0; k0 < K; k0 += 16) {
        float4 av = *(const float4*)(A + (size_t)(rowBase + a_row) * K + k0 + a_kc);
        int c = colBase + b_nc;
        const float* bp;
        if (c < 1024) bp = Wq  + (size_t)(k0 + b_kr) * 1024 + c;
        else          bp = Wkv + (size_t)(k0 + b_kr) * 2048 + (c - 1024);
        float4 bv = *(const float4*)bp;

        As[a_kc + 0][a_row] = av.x;
        As[a_kc + 1][a_row] = av.y;
        As[a_kc + 2][a_row] = av.z;
        As[a_kc + 3][a_row] = av.w;
        *(float4*)&Bs[b_kr][b_nc] = bv;
        __syncthreads();

        #pragma unroll
        for (int kk = 0; kk < 16; ++kk) {
            float4 a4 = *(const float4*)&As[kk][tm];
            float4 b4 = *(const float4*)&Bs[kk][tn];
            float avv[4] = {a4.x, a4.y, a4.z, a4.w};
            float bvv[4] = {b4.x, b4.y, b4.z, b4.w};
            #pragma unroll
            for (int i = 0; i < 4; ++i)
                #pragma unroll
                for (int j = 0; j < 4; ++j)
                    acc[i][j] = fmaf(avv[i], bvv[j], acc[i][j]);
        }
        __syncthreads();
    }

    #pragma unroll
    for (int i = 0; i < 4; ++i) {
        int m = rowBase + tm + i;
        int b = m >> 11, s = m & 2047;
        #pragma unroll
        for (int j = 0; j < 4; ++j) {
            int c = colBase + tn + j;
            int cc = c & 1023;
            int h = cc >> 6, d = cc & 63;
            size_t o = (((size_t)b * HH + h) * SS + s) * DD + d;
            float* dst = (c < 1024) ? qb : (c < 2048) ? kb : vb;
            dst[o] = acc[i][j];
        }
    }
}

// ------------------------------------------------------------------
// Kernel 3: RoPE on q (with scale) and k; lerp v with value_residual
// ------------------------------------------------------------------
__global__ __launch_bounds__(64) void rope_lerp_kernel(
    float* __restrict__ q, float* __restrict__ k, float* __restrict__ v,
    const float* __restrict__ vr, const float* __restrict__ mix)
{
    int idx = blockIdx.x;           // (b*H + h)*S + s
    int s = idx & 2047;
    int d = threadIdx.x;
    size_t off = (size_t)idx * DD + d;

    int m2 = (d >> 1) * 2;
    float inv_freq = powf(10000.f, -(float)m2 * (1.f / 64.f));
    float fr = (float)s * inv_freq;
    float cs, sn;
    sincosf(fr, &sn, &cs);

    float qv = q[off] * 0.125f;
    float qp = __shfl_xor(qv, 1);
    float qr = (d & 1) ? qp : -qp;
    q[off] = qv * cs + qr * sn;

    float kv = k[off];
    float kp = __shfl_xor(kv, 1);
    float kr = (d & 1) ? kp : -kp;
    k[off] = kv * cs + kr * sn;

    float vv = v[off];
    float mxv = mix[idx];
    v[off] = vv + mxv * (vr[off] - vv);
}

// ------------------------------------------------------------------
// Kernel 4: flash-style windowed attention
// grid (S/64, B*H), 256 threads, 64-query tile, 9 x 64-key tiles
// ------------------------------------------------------------------
__global__ __launch_bounds__(256) void attn_flash(
    const float* __restrict__ qb, const float* __restrict__ kb,
    const float* __restrict__ vb, const int* __restrict__ ep,
    const float* __restrict__ gate, float* __restrict__ ao)
{
    int qt = blockIdx.x;            // 0..31
    int bh = blockIdx.y;            // 0..31
    int b  = bh >> 4, h = bh & 15;
    int q0 = qt * 64;
    int tid = threadIdx.x;
    int tr = tid >> 4, tc = tid & 15;

    __shared__ float Qd[64][64];      // Q transposed [d][r]
    __shared__ float KdP[64 * 68];    // K transposed [d][c] (ld 68); later P [r][j] (ld 68)
    __shared__ float Vs[64][64];      // [j][d]
    __shared__ int   epj[64];

    // load Q transposed (once per block)
    {
        int row = tid >> 2;             // 0..63
        int cg  = (tid & 3) * 4;        // 0,4,8,12
        const float* src = qb + ((size_t)bh * SS + q0 + row) * DD;
        #pragma unroll
        for (int u = 0; u < 4; ++u) {
            float4 v4 = *(const float4*)(src + 16 * u + cg);
            Qd[16 * u + cg + 0][row] = v4.x;
            Qd[16 * u + cg + 1][row] = v4.y;
            Qd[16 * u + cg + 2][row] = v4.z;
            Qd[16 * u + cg + 3][row] = v4.w;
        }
    }
    int epi[4];
    #pragma unroll
    for (int ii = 0; ii < 4; ++ii) epi[ii] = ep[b * SS + q0 + 4 * tr + ii];

    float O[4][4];
    float m[4], l[4];
    #pragma unroll
    for (int ii = 0; ii < 4; ++ii) {
        m[ii] = -1e30f; l[ii] = 0.f;
        #pragma unroll
        for (int dd = 0; dd < 4; ++dd) O[ii][dd] = 0.f;
    }

    int t0 = (qt < 8) ? (8 - qt) : 0;
    for (int t = t0; t < 9; ++t) {
        int jbase = 64 * (qt - 8 + t);      // >= 0 for t >= t0
        // stage K (transposed) + V (row-major) + episode ids
        {
            int row = tid >> 2;
            int cg  = (tid & 3) * 4;
            const float* ksrc = kb + ((size_t)bh * SS + jbase + row) * DD;
            #pragma unroll
            for (int u = 0; u < 4; ++u) {
                float4 v4 = *(const float4*)(ksrc + 16 * u + cg);
                KdP[(16 * u + cg + 0) * 68 + row] = v4.x;
                KdP[(16 * u + cg + 1) * 68 + row] = v4.y;
                KdP[(16 * u + cg + 2) * 68 + row] = v4.z;
                KdP[(16 * u + cg + 3) * 68 + row] = v4.w;
            }
            int vrow = tid >> 4;            // 0..15
            int vc   = (tid & 15) * 4;
            #pragma unroll
            for (int u = 0; u < 4; ++u) {
                const float* vsrc = vb + ((size_t)bh * SS + jbase + vrow + 16 * u) * DD + vc;
                *(float4*)&Vs[vrow + 16 * u][vc] = *(const float4*)vsrc;
            }
            if (tid < 64) epj[tid] = ep[b * SS + jbase + tid];
        }
        __syncthreads();

        // S = Q @ K^T  (4x4 microtile)
        float acc[4][4];
        #pragma unroll
        for (int ii = 0; ii < 4; ++ii)
            #pragma unroll
            for (int jj = 0; jj < 4; ++jj) acc[ii][jj] = 0.f;
        #pragma unroll 8
        for (int d = 0; d < 64; ++d) {
            float4 a4 = *(const float4*)&Qd[d][4 * tr];
            float4 b4 = *(const float4*)&KdP[d * 68 + 4 * tc];
            float av[4]  = {a4.x, a4.y, a4.z, a4.w};
            float bvv[4] = {b4.x, b4.y, b4.z, b4.w};
            #pragma unroll
            for (int ii = 0; ii < 4; ++ii)
                #pragma unroll
                for (int jj = 0; jj < 4; ++jj)
                    acc[ii][jj] = fmaf(av[ii], bvv[jj], acc[ii][jj]);
        }
        // mask: window + episode
        #pragma unroll
        for (int ii = 0; ii < 4; ++ii) {
            int i = q0 + 4 * tr + ii;
            #pragma unroll
            for (int jj = 0; jj < 4; ++jj) {
                int j = jbase + 4 * tc + jj;
                int dist = i - j;
                bool bad = (dist < 0) || (dist > WINDOW) || (epj[4 * tc + jj] != epi[ii]);
                if (bad) acc[ii][jj] = -1e30f;
            }
        }
        __syncthreads();    // all K reads done before P overwrites KdP

        // online softmax; write P into KdP (ld 68)
        #pragma unroll
        for (int ii = 0; ii < 4; ++ii) {
            float lm = fmaxf(fmaxf(acc[ii][0], acc[ii][1]), fmaxf(acc[ii][2], acc[ii][3]));
            lm = fmaxf(lm, __shfl_xor(lm, 1, 16));
            lm = fmaxf(lm, __shfl_xor(lm, 2, 16));
            lm = fmaxf(lm, __shfl_xor(lm, 4, 16));
            lm = fmaxf(lm, __shfl_xor(lm, 8, 16));
            float mnew = fmaxf(m[ii], lm);
            float scale = __expf(m[ii] - mnew);
            float p0 = (acc[ii][0] < -1e29f) ? 0.f : __expf(acc[ii][0] - mnew);
            float p1 = (acc[ii][1] < -1e29f) ? 0.f : __expf(acc[ii][1] - mnew);
            float p2 = (acc[ii][2] < -1e29f) ? 0.f : __expf(acc[ii][2] - mnew);
            float p3 = (acc[ii][3] < -1e29f) ? 0.f : __expf(acc[ii][3] - mnew);
            float ls = p0 + p1 + p2 + p3;
            ls += __shfl_xor(ls, 1, 16);
            ls += __shfl_xor(ls, 2, 16);
            ls += __shfl_xor(ls, 4, 16);
            ls += __shfl_xor(ls, 8, 16);
            l[ii] = l[ii] * scale + ls;
            m[ii] = mnew;
            #pragma unroll
            for (int dd = 0; dd < 4; ++dd) O[ii][dd] *= scale;
            *(float4*)&KdP[(4 * tr + ii) * 68 + 4 * tc] = make_float4(p0, p1, p2, p3);
        }
        __syncthreads();

        // O += P @ V
        #pragma unroll 4
        for (int g = 0; g < 16; ++g) {
            float4 pq[4];
            #pragma unroll
            for (int ii = 0; ii < 4; ++ii)
                pq[ii] = *(const float4*)&KdP[(4 * tr + ii) * 68 + 4 * g];
            float pr[4][4] = {
                {pq[0].x, pq[0].y, pq[0].z, pq[0].w},
                {pq[1].x, pq[1].y, pq[1].z, pq[1].w},
                {pq[2].x, pq[2].y, pq[2].z, pq[2].w},
                {pq[3].x, pq[3].y, pq[3].z, pq[3].w}};
            #pragma unroll
            for (int jj = 0; jj < 4; ++jj) {
                float4 vv = *(const float4*)&Vs[4 * g + jj][4 * tc];
                float vvv[4] = {vv.x, vv.y, vv.z, vv.w};
                #pragma unroll
                for (int ii = 0; ii < 4; ++ii)
                    #pragma unroll
                    for (int dd = 0; dd < 4; ++dd)
                        O[ii][dd] = fmaf(pr[ii][jj], vvv[dd], O[ii][dd]);
            }
        }
        __syncthreads();    // PV done before next tile overwrites KdP/Vs
    }

    // epilogue: normalize, gate, store to ao (b, s, h, d)
    #pragma unroll
    for (int ii = 0; ii < 4; ++ii) {
        int i = q0 + 4 * tr + ii;
        float g = gate[(size_t)bh * SS + i] / l[ii];
        float4 o4 = make_float4(O[ii][0] * g, O[ii][1] * g, O[ii][2] * g, O[ii][3] * g);
        *(float4*)(ao + (((size_t)b * SS + i) * HH + h) * DD + 4 * tc) = o4;
    }
}

// ------------------------------------------------------------------
// Kernel 5: output GEMM  ao(4096x1024) @ Wo(1024x1024) -> out
// ------------------------------------------------------------------
__global__ __launch_bounds__(256) void gemm_out(
    const float* __restrict__ A, const float* __restrict__ Bm,
    float* __restrict__ C)
{
    const int K = 1024, N = 1024;
    int colBase = blockIdx.x * 64;
    int rowBase = blockIdx.y * 64;
    int tid = threadIdx.x;

    __shared__ float As[16][64];
    __shared__ float Bs[16][68];

    int a_row = tid >> 2;
    int a_kc  = (tid & 3) * 4;
    int b_kr  = tid >> 4;
    int b_nc  = (tid & 15) * 4;
    int tm = (tid >> 4) * 4;
    int tn = (tid & 15) * 4;

    float acc[4][4];
    #pragma unroll
    for (int i = 0; i < 4; ++i)
        #pragma unroll
        for (int j = 0; j < 4; ++j) acc[i][j] = 0.f;

    for (int k0 = 0; k0 < K; k0 += 16) {
        float4 av = *(const float4*)(A + (size_t)(rowBase + a_row) * K + k0 + a_kc);
        float4 bv = *(const float4*)(Bm + (size_t)(k0 + b_kr) * N + colBase + b_nc);
        As[a_kc + 0][a_row] = av.x;
        As[a_kc + 1][a_row] = av.y;
        As[a_kc + 2][a_row] = av.z;
        As[a_kc + 3][a_row] = av.w;
        *(float4*)&Bs[b_kr][b_nc] = bv;
        __syncthreads();

        #pragma unroll
        for (int kk = 0; kk < 16; ++kk) {
            float4 a4 = *(const float4*)&As[kk][tm];
            float4 b4 = *(const float4*)&Bs[kk][tn];
            float avv[4] = {a4.x, a4.y, a4.z, a4.w};
            float bvv[4] = {b4.x, b4.y, b4.z, b4.w};
            #pragma unroll
            for (int i = 0; i < 4; ++i)
                #pragma unroll
                for (int j = 0; j < 4; ++j)
                    acc[i][j] = fmaf(avv[i], bvv[j], acc[i][j]);
        }
        __syncthreads();
    }

    #pragma unroll
    for (int i = 0; i < 4; ++i) {
        float* crow = C + (size_t)(rowBase + tm + i) * N + colBase + tn;
        #pragma unroll
        for (int j = 0; j < 4; ++j) crow[j] = acc[i][j];
    }
}

// ------------------------------------------------------------------
extern "C" void kernel_launch(void* const* d_in, const int* in_sizes, int n_in,
                              void* d_out, int out_size, void* d_ws, size_t ws_size,
                              hipStream_t stream)
{
    const float* tokens = (const float*)d_in[0];
    const float* vres   = (const float*)d_in[1];
    const int*   ep     = (const int*)d_in[2];
    const float* Wq     = (const float*)d_in[3];
    const float* Wkv    = (const float*)d_in[4];
    const float* Wo     = (const float*)d_in[5];
    const float* Wg     = (const float*)d_in[6];
    const float* Wmix   = (const float*)d_in[7];
    float* out = (float*)d_out;

    const size_t BHSD = (size_t)BB * HH * SS * DD;
    float* ws   = (float*)d_ws;
    float* qb   = ws;
    float* kb   = qb + BHSD;
    float* vb   = kb + BHSD;
    float* ao   = vb + BHSD;
    float* gatep = ao + BHSD;
    float* mixp  = gatep + (size_t)BB * HH * SS;

    mixgate_kernel<<<BB * SS, 256, 0, stream>>>(tokens, Wg, Wmix, gatep, mixp);
    gemm_proj<<<dim3(48, 64), 256, 0, stream>>>(tokens, Wq, Wkv, qb, kb, vb);
    rope_lerp_kernel<<<BB * HH * SS, 64, 0, stream>>>(qb, kb, vb, vres, mixp);
    attn_flash<<<dim3(SS / 64, BB * HH), 256, 0, stream>>>(qb, kb, vb, ep, gatep, ao);
    gemm_out<<<dim3(16, 64), 256, 0, stream>>>(ao, Wo, out);
}

// Round 3
// 397.509 us; speedup vs baseline: 5.5126x; 1.9411x over previous
//
#include <hip/hip_runtime.h>
#include <math.h>

#define BB 2
#define SS 2048
#define DIMM 1024
#define HH 16
#define DD 64
#define WINDOW 512

typedef __bf16 bf16x8 __attribute__((ext_vector_type(8)));
typedef float f32x4 __attribute__((ext_vector_type(4)));

__device__ __forceinline__ unsigned short f2bf(float f) {
    unsigned int u = __float_as_uint(f);
    u = (u + 0x7FFFu + ((u >> 16) & 1u)) >> 16;
    return (unsigned short)u;
}

__device__ __forceinline__ void async_cp16(unsigned short* lds_dst, const unsigned short* g_src) {
    __builtin_amdgcn_global_load_lds(
        (const __attribute__((address_space(1))) unsigned int*)g_src,
        (__attribute__((address_space(3))) unsigned int*)lds_dst, 16, 0, 0);
}

// ------------------------------------------------------------------
// fp32 -> bf16 flat convert (tokens)
// ------------------------------------------------------------------
__global__ __launch_bounds__(256) void cvt_bf16_kernel(
    const float* __restrict__ src, unsigned short* __restrict__ dst, int n4)
{
    for (int i = blockIdx.x * 256 + threadIdx.x; i < n4; i += gridDim.x * 256) {
        float4 v = ((const float4*)src)[i];
        ushort4 o;
        o.x = f2bf(v.x); o.y = f2bf(v.y); o.z = f2bf(v.z); o.w = f2bf(v.w);
        ((ushort4*)dst)[i] = o;
    }
}

// ------------------------------------------------------------------
// transpose + convert: src fp32 [R][C] -> dst bf16 [C][R]
// block (32,8), grid (C/32, R/32)
// ------------------------------------------------------------------
__global__ __launch_bounds__(256) void transpose_cvt_kernel(
    const float* __restrict__ src, unsigned short* __restrict__ dst, int R, int C)
{
    __shared__ float t[32][33];
    int c0 = blockIdx.x * 32, r0 = blockIdx.y * 32;
    int tx = threadIdx.x, ty = threadIdx.y;
    #pragma unroll
    for (int u = 0; u < 4; ++u)
        t[ty + 8 * u][tx] = src[(size_t)(r0 + ty + 8 * u) * C + c0 + tx];
    __syncthreads();
    #pragma unroll
    for (int u = 0; u < 4; ++u)
        dst[(size_t)(c0 + ty + 8 * u) * R + r0 + tx] = f2bf(t[tx][ty + 8 * u]);
}

// ------------------------------------------------------------------
// mix & gate
// ------------------------------------------------------------------
__global__ __launch_bounds__(256) void mixgate_kernel(
    const float* __restrict__ tokens, const float* __restrict__ Wg,
    const float* __restrict__ Wmix, float* __restrict__ gate,
    float* __restrict__ mix)
{
    int m = blockIdx.x;
    int b = m >> 11, s = m & 2047;
    int tid = threadIdx.x;
    __shared__ float tok[1024];
    const float4* t4 = (const float4*)(tokens + (size_t)m * DIMM);
    ((float4*)tok)[tid] = t4[tid];
    __syncthreads();

    int out  = tid >> 3;
    int part = tid & 7;
    int h    = out & 15;
    const float* W = (out < 16) ? Wg : Wmix;
    float acc = 0.f;
    int k0 = part * 128;
    #pragma unroll 4
    for (int kk = k0; kk < k0 + 128; ++kk)
        acc += tok[kk] * W[kk * HH + h];
    acc += __shfl_down(acc, 4, 8);
    acc += __shfl_down(acc, 2, 8);
    acc += __shfl_down(acc, 1, 8);
    if (part == 0) {
        float sg = 1.f / (1.f + __expf(-acc));
        float* dst = (out < 16) ? gate : mix;
        dst[((size_t)b * HH + h) * SS + s] = sg;
    }
}

// ------------------------------------------------------------------
// bf16 MFMA GEMM: A [M][1024] bf16 row-major, Bt [N][1024] bf16 (N-major)
// 128x128 tile, BK=32, 4 waves, 4x4 16x16x32 fragments per wave.
// EPI=0: plain store C fp32 [M][1024]; EPI=1: scatter q/k/v (B,H,S,D)
// ------------------------------------------------------------------
template<int EPI>
__global__ __launch_bounds__(256) void gemm_mfma(
    const unsigned short* __restrict__ A, const unsigned short* __restrict__ Bt,
    float* __restrict__ o0, float* __restrict__ o1, float* __restrict__ o2)
{
    const int K = 1024;
    int nbase = blockIdx.x * 128;
    int mbase = blockIdx.y * 128;
    int tid = threadIdx.x;
    int lane = tid & 63;
    int wave = tid >> 6;
    int wr = wave >> 1, wc = wave & 1;
    int fr = lane & 15, hi = lane >> 4;

    __shared__ unsigned short As[128 * 32];
    __shared__ unsigned short Bs[128 * 32];

    // staging: thread t covers phys 16B slot t (shot0 rows 0-63, shot1 rows 64-127)
    // LDS layout [row][32] row-major; slot-in-row XOR-swizzled by (row>>1)&3
    int srow = tid >> 2;
    int sp   = tid & 3;
    int scol = (sp ^ ((srow >> 1) & 3)) * 8;   // same for row and row+64
    const unsigned short* agp0 = A  + (size_t)(mbase + srow) * K + scol;
    const unsigned short* agp1 = A  + (size_t)(mbase + srow + 64) * K + scol;
    const unsigned short* bgp0 = Bt + (size_t)(nbase + srow) * K + scol;
    const unsigned short* bgp1 = Bt + (size_t)(nbase + srow + 64) * K + scol;
    unsigned short* al0 = &As[tid * 8];
    unsigned short* al1 = &As[2048 + tid * 8];
    unsigned short* bl0 = &Bs[tid * 8];
    unsigned short* bl1 = &Bs[2048 + tid * 8];

    f32x4 acc[4][4];
    #pragma unroll
    for (int m_ = 0; m_ < 4; ++m_)
        #pragma unroll
        for (int n_ = 0; n_ < 4; ++n_)
            acc[m_][n_] = (f32x4){0.f, 0.f, 0.f, 0.f};

    int aidx[4], bidx[4];
    #pragma unroll
    for (int m_ = 0; m_ < 4; ++m_) {
        int row = wr * 64 + m_ * 16 + fr;
        aidx[m_] = row * 32 + (hi ^ ((row >> 1) & 3)) * 8;
    }
    #pragma unroll
    for (int n_ = 0; n_ < 4; ++n_) {
        int row = wc * 64 + n_ * 16 + fr;
        bidx[n_] = row * 32 + (hi ^ ((row >> 1) & 3)) * 8;
    }

    for (int k0 = 0; k0 < K; k0 += 32) {
        __syncthreads();                 // previous tile's reads done
        async_cp16(al0, agp0 + k0);
        async_cp16(al1, agp1 + k0);
        async_cp16(bl0, bgp0 + k0);
        async_cp16(bl1, bgp1 + k0);
        __syncthreads();                 // staging complete (vmcnt drained)

        bf16x8 af[4], bfr[4];
        #pragma unroll
        for (int m_ = 0; m_ < 4; ++m_) af[m_] = *(const bf16x8*)&As[aidx[m_]];
        #pragma unroll
        for (int n_ = 0; n_ < 4; ++n_) bfr[n_] = *(const bf16x8*)&Bs[bidx[n_]];
        #pragma unroll
        for (int m_ = 0; m_ < 4; ++m_)
            #pragma unroll
            for (int n_ = 0; n_ < 4; ++n_)
                acc[m_][n_] = __builtin_amdgcn_mfma_f32_16x16x32_bf16(
                    af[m_], bfr[n_], acc[m_][n_], 0, 0, 0);
    }

    #pragma unroll
    for (int m_ = 0; m_ < 4; ++m_) {
        #pragma unroll
        for (int n_ = 0; n_ < 4; ++n_) {
            int c = nbase + wc * 64 + n_ * 16 + fr;
            #pragma unroll
            for (int j = 0; j < 4; ++j) {
                int mg = mbase + wr * 64 + m_ * 16 + hi * 4 + j;
                float v = acc[m_][n_][j];
                if (EPI == 0) {
                    o0[(size_t)mg * 1024 + c] = v;
                } else {
                    int b = mg >> 11, s = mg & 2047;
                    int cc = c & 1023, h = cc >> 6, d = cc & 63;
                    float* dst = (c < 1024) ? o0 : (c < 2048) ? o1 : o2;
                    dst[(((size_t)b * HH + h) * SS + s) * DD + d] = v;
                }
            }
        }
    }
}

// ------------------------------------------------------------------
// RoPE + V lerp
// ------------------------------------------------------------------
__global__ __launch_bounds__(64) void rope_lerp_kernel(
    float* __restrict__ q, float* __restrict__ k, float* __restrict__ v,
    const float* __restrict__ vr, const float* __restrict__ mix)
{
    int idx = blockIdx.x;
    int s = idx & 2047;
    int d = threadIdx.x;
    size_t off = (size_t)idx * DD + d;

    int m2 = (d >> 1) * 2;
    float inv_freq = powf(10000.f, -(float)m2 * (1.f / 64.f));
    float fr = (float)s * inv_freq;
    float cs, sn;
    sincosf(fr, &sn, &cs);

    float qv = q[off] * 0.125f;
    float qp = __shfl_xor(qv, 1);
    float qr = (d & 1) ? qp : -qp;
    q[off] = qv * cs + qr * sn;

    float kv = k[off];
    float kp = __shfl_xor(kv, 1);
    float kr = (d & 1) ? kp : -kp;
    k[off] = kv * cs + kr * sn;

    float vv = v[off];
    float mxv = mix[idx];
    v[off] = vv + mxv * (vr[off] - vv);
}

// ------------------------------------------------------------------
// flash windowed attention (fp32 compute), bf16 ao output
// ------------------------------------------------------------------
__global__ __launch_bounds__(256) void attn_flash(
    const float* __restrict__ qb, const float* __restrict__ kb,
    const float* __restrict__ vb, const int* __restrict__ ep,
    const float* __restrict__ gate, unsigned short* __restrict__ ao)
{
    int qt = blockIdx.x;
    int bh = blockIdx.y;
    int b  = bh >> 4, h = bh & 15;
    int q0 = qt * 64;
    int tid = threadIdx.x;
    int tr = tid >> 4, tc = tid & 15;

    __shared__ float Qd[64][64];
    __shared__ float KdP[64 * 68];
    __shared__ float Vs[64][64];
    __shared__ int   epj[64];

    {
        int row = tid >> 2;
        int cg  = (tid & 3) * 4;
        const float* src = qb + ((size_t)bh * SS + q0 + row) * DD;
        #pragma unroll
        for (int u = 0; u < 4; ++u) {
            float4 v4 = *(const float4*)(src + 16 * u + cg);
            Qd[16 * u + cg + 0][row] = v4.x;
            Qd[16 * u + cg + 1][row] = v4.y;
            Qd[16 * u + cg + 2][row] = v4.z;
            Qd[16 * u + cg + 3][row] = v4.w;
        }
    }
    int epi[4];
    #pragma unroll
    for (int ii = 0; ii < 4; ++ii) epi[ii] = ep[b * SS + q0 + 4 * tr + ii];

    float O[4][4];
    float m[4], l[4];
    #pragma unroll
    for (int ii = 0; ii < 4; ++ii) {
        m[ii] = -1e30f; l[ii] = 0.f;
        #pragma unroll
        for (int dd = 0; dd < 4; ++dd) O[ii][dd] = 0.f;
    }

    int t0 = (qt < 8) ? (8 - qt) : 0;
    for (int t = t0; t < 9; ++t) {
        int jbase = 64 * (qt - 8 + t);
        {
            int row = tid >> 2;
            int cg  = (tid & 3) * 4;
            const float* ksrc = kb + ((size_t)bh * SS + jbase + row) * DD;
            #pragma unroll
            for (int u = 0; u < 4; ++u) {
                float4 v4 = *(const float4*)(ksrc + 16 * u + cg);
                KdP[(16 * u + cg + 0) * 68 + row] = v4.x;
                KdP[(16 * u + cg + 1) * 68 + row] = v4.y;
                KdP[(16 * u + cg + 2) * 68 + row] = v4.z;
                KdP[(16 * u + cg + 3) * 68 + row] = v4.w;
            }
            int vrow = tid >> 4;
            int vc   = (tid & 15) * 4;
            #pragma unroll
            for (int u = 0; u < 4; ++u) {
                const float* vsrc = vb + ((size_t)bh * SS + jbase + vrow + 16 * u) * DD + vc;
                *(float4*)&Vs[vrow + 16 * u][vc] = *(const float4*)vsrc;
            }
            if (tid < 64) epj[tid] = ep[b * SS + jbase + tid];
        }
        __syncthreads();

        float acc[4][4];
        #pragma unroll
        for (int ii = 0; ii < 4; ++ii)
            #pragma unroll
            for (int jj = 0; jj < 4; ++jj) acc[ii][jj] = 0.f;
        #pragma unroll 8
        for (int d = 0; d < 64; ++d) {
            float4 a4 = *(const float4*)&Qd[d][4 * tr];
            float4 b4 = *(const float4*)&KdP[d * 68 + 4 * tc];
            float av[4]  = {a4.x, a4.y, a4.z, a4.w};
            float bvv[4] = {b4.x, b4.y, b4.z, b4.w};
            #pragma unroll
            for (int ii = 0; ii < 4; ++ii)
                #pragma unroll
                for (int jj = 0; jj < 4; ++jj)
                    acc[ii][jj] = fmaf(av[ii], bvv[jj], acc[ii][jj]);
        }
        #pragma unroll
        for (int ii = 0; ii < 4; ++ii) {
            int i = q0 + 4 * tr + ii;
            #pragma unroll
            for (int jj = 0; jj < 4; ++jj) {
                int j = jbase + 4 * tc + jj;
                int dist = i - j;
                bool bad = (dist < 0) || (dist > WINDOW) || (epj[4 * tc + jj] != epi[ii]);
                if (bad) acc[ii][jj] = -1e30f;
            }
        }
        __syncthreads();

        #pragma unroll
        for (int ii = 0; ii < 4; ++ii) {
            float lm = fmaxf(fmaxf(acc[ii][0], acc[ii][1]), fmaxf(acc[ii][2], acc[ii][3]));
            lm = fmaxf(lm, __shfl_xor(lm, 1, 16));
            lm = fmaxf(lm, __shfl_xor(lm, 2, 16));
            lm = fmaxf(lm, __shfl_xor(lm, 4, 16));
            lm = fmaxf(lm, __shfl_xor(lm, 8, 16));
            float mnew = fmaxf(m[ii], lm);
            float scale = __expf(m[ii] - mnew);
            float p0 = (acc[ii][0] < -1e29f) ? 0.f : __expf(acc[ii][0] - mnew);
            float p1 = (acc[ii][1] < -1e29f) ? 0.f : __expf(acc[ii][1] - mnew);
            float p2 = (acc[ii][2] < -1e29f) ? 0.f : __expf(acc[ii][2] - mnew);
            float p3 = (acc[ii][3] < -1e29f) ? 0.f : __expf(acc[ii][3] - mnew);
            float ls = p0 + p1 + p2 + p3;
            ls += __shfl_xor(ls, 1, 16);
            ls += __shfl_xor(ls, 2, 16);
            ls += __shfl_xor(ls, 4, 16);
            ls += __shfl_xor(ls, 8, 16);
            l[ii] = l[ii] * scale + ls;
            m[ii] = mnew;
            #pragma unroll
            for (int dd = 0; dd < 4; ++dd) O[ii][dd] *= scale;
            *(float4*)&KdP[(4 * tr + ii) * 68 + 4 * tc] = make_float4(p0, p1, p2, p3);
        }
        __syncthreads();

        #pragma unroll 4
        for (int g = 0; g < 16; ++g) {
            float4 pq[4];
            #pragma unroll
            for (int ii = 0; ii < 4; ++ii)
                pq[ii] = *(const float4*)&KdP[(4 * tr + ii) * 68 + 4 * g];
            float pr[4][4] = {
                {pq[0].x, pq[0].y, pq[0].z, pq[0].w},
                {pq[1].x, pq[1].y, pq[1].z, pq[1].w},
                {pq[2].x, pq[2].y, pq[2].z, pq[2].w},
                {pq[3].x, pq[3].y, pq[3].z, pq[3].w}};
            #pragma unroll
            for (int jj = 0; jj < 4; ++jj) {
                float4 vv = *(const float4*)&Vs[4 * g + jj][4 * tc];
                float vvv[4] = {vv.x, vv.y, vv.z, vv.w};
                #pragma unroll
                for (int ii = 0; ii < 4; ++ii)
                    #pragma unroll
                    for (int dd = 0; dd < 4; ++dd)
                        O[ii][dd] = fmaf(pr[ii][jj], vvv[dd], O[ii][dd]);
            }
        }
        __syncthreads();
    }

    #pragma unroll
    for (int ii = 0; ii < 4; ++ii) {
        int i = q0 + 4 * tr + ii;
        float g = gate[(size_t)bh * SS + i] / l[ii];
        ushort4 o4;
        o4.x = f2bf(O[ii][0] * g);
        o4.y = f2bf(O[ii][1] * g);
        o4.z = f2bf(O[ii][2] * g);
        o4.w = f2bf(O[ii][3] * g);
        *(ushort4*)(ao + (((size_t)b * SS + i) * HH + h) * DD + 4 * tc) = o4;
    }
}

// ------------------------------------------------------------------
extern "C" void kernel_launch(void* const* d_in, const int* in_sizes, int n_in,
                              void* d_out, int out_size, void* d_ws, size_t ws_size,
                              hipStream_t stream)
{
    const float* tokens = (const float*)d_in[0];
    const float* vres   = (const float*)d_in[1];
    const int*   ep     = (const int*)d_in[2];
    const float* Wq     = (const float*)d_in[3];
    const float* Wkv    = (const float*)d_in[4];
    const float* Wo     = (const float*)d_in[5];
    const float* Wg     = (const float*)d_in[6];
    const float* Wmix   = (const float*)d_in[7];
    float* out = (float*)d_out;

    char* wsb = (char*)d_ws;
    float* qb    = (float*)(wsb + 0);                       // 16 MB
    float* kb    = (float*)(wsb + 16777216);                // 16 MB
    float* vb    = (float*)(wsb + 33554432);                // 16 MB
    float* gatep = (float*)(wsb + 50331648);                // 256 KB
    float* mixp  = (float*)(wsb + 50593792);                // 256 KB
    unsigned short* tokA = (unsigned short*)(wsb + 50855936); // 8 MB (dead after proj)
    unsigned short* aob  = tokA;                              // alias (live after attn)
    unsigned short* BtW  = (unsigned short*)(wsb + 59244544); // 6 MB (dead after proj)
    unsigned short* WotW = BtW;                               // alias (live after attn)

    // converts
    cvt_bf16_kernel<<<2048, 256, 0, stream>>>(tokens, tokA, (BB * SS * DIMM) / 4);
    transpose_cvt_kernel<<<dim3(32, 32), dim3(32, 8), 0, stream>>>(Wq,  BtW,               1024, 1024);
    transpose_cvt_kernel<<<dim3(64, 32), dim3(32, 8), 0, stream>>>(Wkv, BtW + 1024 * 1024, 1024, 2048);

    mixgate_kernel<<<BB * SS, 256, 0, stream>>>(tokens, Wg, Wmix, gatep, mixp);

    gemm_mfma<1><<<dim3(24, 32), 256, 0, stream>>>(tokA, BtW, qb, kb, vb);
    rope_lerp_kernel<<<BB * HH * SS, 64, 0, stream>>>(qb, kb, vb, vres, mixp);
    attn_flash<<<dim3(SS / 64, BB * HH), 256, 0, stream>>>(qb, kb, vb, ep, gatep, aob);

    transpose_cvt_kernel<<<dim3(32, 32), dim3(32, 8), 0, stream>>>(Wo, WotW, 1024, 1024);
    gemm_mfma<0><<<dim3(8, 32), 256, 0, stream>>>(aob, WotW, out, nullptr, nullptr);
}

// Round 4
// 282.887 us; speedup vs baseline: 7.7463x; 1.4052x over previous
//
#include <hip/hip_runtime.h>
#include <math.h>

#define BB 2
#define SS 2048
#define DIMM 1024
#define HH 16
#define DD 64
#define WINDOW 512

typedef __bf16 bf16x8 __attribute__((ext_vector_type(8)));
typedef float f32x4 __attribute__((ext_vector_type(4)));

__device__ __forceinline__ unsigned short f2bf(float f) {
    unsigned int u = __float_as_uint(f);
    u = (u + 0x7FFFu + ((u >> 16) & 1u)) >> 16;
    return (unsigned short)u;
}
__device__ __forceinline__ float bf2f(unsigned short u) {
    return __uint_as_float((unsigned int)u << 16);
}

__device__ __forceinline__ void async_cp16(unsigned short* lds_dst, const unsigned short* g_src) {
    __builtin_amdgcn_global_load_lds(
        (const __attribute__((address_space(1))) unsigned int*)g_src,
        (__attribute__((address_space(3))) unsigned int*)lds_dst, 16, 0, 0);
}

// ------------------------------------------------------------------
// fp32 -> bf16 flat convert (tokens)
// ------------------------------------------------------------------
__global__ __launch_bounds__(256) void cvt_bf16_kernel(
    const float* __restrict__ src, unsigned short* __restrict__ dst, int n4)
{
    for (int i = blockIdx.x * 256 + threadIdx.x; i < n4; i += gridDim.x * 256) {
        float4 v = ((const float4*)src)[i];
        ushort4 o;
        o.x = f2bf(v.x); o.y = f2bf(v.y); o.z = f2bf(v.z); o.w = f2bf(v.w);
        ((ushort4*)dst)[i] = o;
    }
}

// ------------------------------------------------------------------
// transpose + convert: src fp32 [R][C] -> dst bf16 [C][R]
// ------------------------------------------------------------------
__global__ __launch_bounds__(256) void transpose_cvt_kernel(
    const float* __restrict__ src, unsigned short* __restrict__ dst, int R, int C)
{
    __shared__ float t[32][33];
    int c0 = blockIdx.x * 32, r0 = blockIdx.y * 32;
    int tx = threadIdx.x, ty = threadIdx.y;
    #pragma unroll
    for (int u = 0; u < 4; ++u)
        t[ty + 8 * u][tx] = src[(size_t)(r0 + ty + 8 * u) * C + c0 + tx];
    __syncthreads();
    #pragma unroll
    for (int u = 0; u < 4; ++u)
        dst[(size_t)(c0 + ty + 8 * u) * R + r0 + tx] = f2bf(t[tx][ty + 8 * u]);
}

// ------------------------------------------------------------------
// mix & gate
// ------------------------------------------------------------------
__global__ __launch_bounds__(256) void mixgate_kernel(
    const float* __restrict__ tokens, const float* __restrict__ Wg,
    const float* __restrict__ Wmix, float* __restrict__ gate,
    float* __restrict__ mix)
{
    int m = blockIdx.x;
    int b = m >> 11, s = m & 2047;
    int tid = threadIdx.x;
    __shared__ float tok[1024];
    const float4* t4 = (const float4*)(tokens + (size_t)m * DIMM);
    ((float4*)tok)[tid] = t4[tid];
    __syncthreads();

    int out  = tid >> 3;
    int part = tid & 7;
    int h    = out & 15;
    const float* W = (out < 16) ? Wg : Wmix;
    float acc = 0.f;
    int k0 = part * 128;
    #pragma unroll 4
    for (int kk = k0; kk < k0 + 128; ++kk)
        acc += tok[kk] * W[kk * HH + h];
    acc += __shfl_down(acc, 4, 8);
    acc += __shfl_down(acc, 2, 8);
    acc += __shfl_down(acc, 1, 8);
    if (part == 0) {
        float sg = 1.f / (1.f + __expf(-acc));
        float* dst = (out < 16) ? gate : mix;
        dst[((size_t)b * HH + h) * SS + s] = sg;
    }
}

// ------------------------------------------------------------------
// episode start: epstart[b][i] = first index of i's episode (sorted ids)
// ------------------------------------------------------------------
__global__ __launch_bounds__(256) void epstart_kernel(
    const int* __restrict__ ep, int* __restrict__ epstart)
{
    int idx = blockIdx.x * 256 + threadIdx.x;   // b*S + i
    int b = idx >> 11, i = idx & 2047;
    const int* e = ep + b * SS;
    int v = e[i];
    int lo = 0, hi = i;
    while (lo < hi) {
        int mid = (lo + hi) >> 1;
        if (e[mid] == v) hi = mid; else lo = mid + 1;
    }
    epstart[idx] = lo;
}

// ------------------------------------------------------------------
// bf16 MFMA GEMM: A [M][1024] bf16 row-major, Bt [N][1024] bf16 (N-major)
// EPI=0: C fp32 [M][1024]; EPI=1: scatter bf16 q/k/v (B,H,S,D)
// ------------------------------------------------------------------
template<int EPI>
__global__ __launch_bounds__(256) void gemm_mfma(
    const unsigned short* __restrict__ A, const unsigned short* __restrict__ Bt,
    void* __restrict__ o0v, void* __restrict__ o1v, void* __restrict__ o2v)
{
    const int K = 1024;
    int nbase = blockIdx.x * 128;
    int mbase = blockIdx.y * 128;
    int tid = threadIdx.x;
    int lane = tid & 63;
    int wave = tid >> 6;
    int wr = wave >> 1, wc = wave & 1;
    int fr = lane & 15, hi = lane >> 4;

    __shared__ unsigned short As[128 * 32];
    __shared__ unsigned short Bs[128 * 32];

    int srow = tid >> 2;
    int sp   = tid & 3;
    int scol = (sp ^ ((srow >> 1) & 3)) * 8;
    const unsigned short* agp0 = A  + (size_t)(mbase + srow) * K + scol;
    const unsigned short* agp1 = A  + (size_t)(mbase + srow + 64) * K + scol;
    const unsigned short* bgp0 = Bt + (size_t)(nbase + srow) * K + scol;
    const unsigned short* bgp1 = Bt + (size_t)(nbase + srow + 64) * K + scol;
    unsigned short* al0 = &As[tid * 8];
    unsigned short* al1 = &As[2048 + tid * 8];
    unsigned short* bl0 = &Bs[tid * 8];
    unsigned short* bl1 = &Bs[2048 + tid * 8];

    f32x4 acc[4][4];
    #pragma unroll
    for (int m_ = 0; m_ < 4; ++m_)
        #pragma unroll
        for (int n_ = 0; n_ < 4; ++n_)
            acc[m_][n_] = (f32x4){0.f, 0.f, 0.f, 0.f};

    int aidx[4], bidx[4];
    #pragma unroll
    for (int m_ = 0; m_ < 4; ++m_) {
        int row = wr * 64 + m_ * 16 + fr;
        aidx[m_] = row * 32 + (hi ^ ((row >> 1) & 3)) * 8;
    }
    #pragma unroll
    for (int n_ = 0; n_ < 4; ++n_) {
        int row = wc * 64 + n_ * 16 + fr;
        bidx[n_] = row * 32 + (hi ^ ((row >> 1) & 3)) * 8;
    }

    for (int k0 = 0; k0 < K; k0 += 32) {
        __syncthreads();
        async_cp16(al0, agp0 + k0);
        async_cp16(al1, agp1 + k0);
        async_cp16(bl0, bgp0 + k0);
        async_cp16(bl1, bgp1 + k0);
        __syncthreads();

        bf16x8 af[4], bfr[4];
        #pragma unroll
        for (int m_ = 0; m_ < 4; ++m_) af[m_] = *(const bf16x8*)&As[aidx[m_]];
        #pragma unroll
        for (int n_ = 0; n_ < 4; ++n_) bfr[n_] = *(const bf16x8*)&Bs[bidx[n_]];
        #pragma unroll
        for (int m_ = 0; m_ < 4; ++m_)
            #pragma unroll
            for (int n_ = 0; n_ < 4; ++n_)
                acc[m_][n_] = __builtin_amdgcn_mfma_f32_16x16x32_bf16(
                    af[m_], bfr[n_], acc[m_][n_], 0, 0, 0);
    }

    #pragma unroll
    for (int m_ = 0; m_ < 4; ++m_) {
        #pragma unroll
        for (int n_ = 0; n_ < 4; ++n_) {
            int c = nbase + wc * 64 + n_ * 16 + fr;
            #pragma unroll
            for (int j = 0; j < 4; ++j) {
                int mg = mbase + wr * 64 + m_ * 16 + hi * 4 + j;
                float v = acc[m_][n_][j];
                if (EPI == 0) {
                    ((float*)o0v)[(size_t)mg * 1024 + c] = v;
                } else {
                    int b = mg >> 11, s = mg & 2047;
                    int cc = c & 1023, h = cc >> 6, d = cc & 63;
                    unsigned short* dst = (c < 1024) ? (unsigned short*)o0v
                                        : (c < 2048) ? (unsigned short*)o1v
                                                     : (unsigned short*)o2v;
                    dst[(((size_t)b * HH + h) * SS + s) * DD + d] = f2bf(v);
                }
            }
        }
    }
}

// ------------------------------------------------------------------
// RoPE in-place on bf16 q,k; V lerp -> V^T bf16 [bh][d][s]
// grid (S/64, BH), 256 threads, tile 64s x 64d
// ------------------------------------------------------------------
__global__ __launch_bounds__(256) void rope_lerp_kernel(
    unsigned short* __restrict__ q, unsigned short* __restrict__ k,
    const unsigned short* __restrict__ v0, const float* __restrict__ vres,
    const float* __restrict__ mix, unsigned short* __restrict__ vt)
{
    int st = blockIdx.x;
    int bh = blockIdx.y;
    int tid = threadIdx.x;
    int sl = tid >> 2;            // 0..63
    int dg = (tid & 3) * 16;      // 0,16,32,48
    int s = st * 64 + sl;
    size_t rowoff = ((size_t)bh * SS + s) * DD + dg;

    __shared__ unsigned short vtile[64][66];

    union { uint4 v[2]; unsigned short u[16]; } qa, ka, va;
    qa.v[0] = *(const uint4*)(q + rowoff);
    qa.v[1] = *(const uint4*)(q + rowoff + 8);
    ka.v[0] = *(const uint4*)(k + rowoff);
    ka.v[1] = *(const uint4*)(k + rowoff + 8);
    va.v[0] = *(const uint4*)(v0 + rowoff);
    va.v[1] = *(const uint4*)(v0 + rowoff + 8);
    float4 w[4];
    #pragma unroll
    for (int u = 0; u < 4; ++u) w[u] = *(const float4*)(vres + rowoff + 4 * u);
    float mx = mix[(size_t)bh * SS + s];

    #pragma unroll
    for (int u = 0; u < 8; ++u) {
        int d0 = dg + 2 * u;
        float inv_freq = powf(10000.f, -(float)d0 * (1.f / 64.f));
        float fr = (float)s * inv_freq;
        float red = fr - 6.2831853f * floorf(fr * 0.15915494f);
        float cs, sn;
        __sincosf(red, &sn, &cs);
        float x = bf2f(qa.u[2 * u]), y = bf2f(qa.u[2 * u + 1]);
        qa.u[2 * u]     = f2bf((x * cs - y * sn) * 0.125f);
        qa.u[2 * u + 1] = f2bf((y * cs + x * sn) * 0.125f);
        x = bf2f(ka.u[2 * u]); y = bf2f(ka.u[2 * u + 1]);
        ka.u[2 * u]     = f2bf(x * cs - y * sn);
        ka.u[2 * u + 1] = f2bf(y * cs + x * sn);
    }
    *(uint4*)(q + rowoff)     = qa.v[0];
    *(uint4*)(q + rowoff + 8) = qa.v[1];
    *(uint4*)(k + rowoff)     = ka.v[0];
    *(uint4*)(k + rowoff + 8) = ka.v[1];

    #pragma unroll
    for (int e = 0; e < 16; ++e) {
        float vv = bf2f(va.u[e]);
        float wr = ((const float*)w)[e];
        vtile[sl][dg + e] = f2bf(vv + mx * (wr - vv));
    }
    __syncthreads();

    // write V^T rows: thread handles d = tid>>2, s-chunk (tid&3)*16
    int d = tid >> 2;
    int sseg = (tid & 3) * 16;
    union { uint4 v[2]; unsigned short u[16]; } ot;
    #pragma unroll
    for (int e = 0; e < 16; ++e) ot.u[e] = vtile[sseg + e][d];
    unsigned short* dst = vt + ((size_t)bh * DD + d) * SS + st * 64 + sseg;
    *(uint4*)dst = ot.v[0];
    *(uint4*)(dst + 8) = ot.v[1];
}

// ------------------------------------------------------------------
// MFMA flash attention (swapped operands), 4 waves x 16 queries
// grid (S/64, BH)
// ------------------------------------------------------------------
__global__ __launch_bounds__(256) void attn_mfma(
    const unsigned short* __restrict__ qbh, const unsigned short* __restrict__ kbh,
    const unsigned short* __restrict__ vt, const int* __restrict__ epstart,
    const float* __restrict__ gate, unsigned short* __restrict__ ao)
{
    int qt = blockIdx.x, bh = blockIdx.y;
    int b = bh >> 4, h = bh & 15;
    int q0 = qt * 64;
    int tid = threadIdx.x;
    int wave = tid >> 6, lane = tid & 63;
    int lq = lane & 15, lg = lane >> 4;
    int i = q0 + wave * 16 + lq;

    alignas(16) __shared__ unsigned short P_lds[4][16][72];

    // Q fragments (B-operand: col=q, K=d)
    const unsigned short* qrow = qbh + ((size_t)bh * SS + i) * DD + lg * 8;
    bf16x8 bq0 = *(const bf16x8*)qrow;
    bf16x8 bq1 = *(const bf16x8*)(qrow + 32);

    int jmin = i - WINDOW;
    int es = epstart[b * SS + i];
    if (es > jmin) jmin = es;
    float gi = gate[(size_t)bh * SS + i];

    float m = -1e30f, l = 0.f;
    f32x4 o[4];
    #pragma unroll
    for (int n = 0; n < 4; ++n) o[n] = (f32x4){0.f, 0.f, 0.f, 0.f};

    int t0 = (qt < 8) ? (8 - qt) : 0;
    for (int t = t0; t < 9; ++t) {
        int jbase = 64 * (qt - 8 + t);

        // S^T = K @ Q : acc[n] holds j-rows 16n+lg*4+r, col q (this lane)
        f32x4 acc[4];
        #pragma unroll
        for (int n = 0; n < 4; ++n) acc[n] = (f32x4){0.f, 0.f, 0.f, 0.f};
        const unsigned short* kbase = kbh + ((size_t)bh * SS + jbase) * DD + lg * 8;
        #pragma unroll
        for (int n = 0; n < 4; ++n) {
            const unsigned short* kr = kbase + (size_t)(16 * n + lq) * DD;
            acc[n] = __builtin_amdgcn_mfma_f32_16x16x32_bf16(
                *(const bf16x8*)kr, bq0, acc[n], 0, 0, 0);
            acc[n] = __builtin_amdgcn_mfma_f32_16x16x32_bf16(
                *(const bf16x8*)(kr + 32), bq1, acc[n], 0, 0, 0);
        }

        // mask (window + episode via epstart)
        int jb = jbase + lg * 4;
        #pragma unroll
        for (int n = 0; n < 4; ++n)
            #pragma unroll
            for (int r = 0; r < 4; ++r) {
                int j = jb + 16 * n + r;
                if (j < jmin || j > i) acc[n][r] = -3e38f;
            }

        // online softmax (per-lane scalar m,l)
        float tm = -3e38f;
        #pragma unroll
        for (int n = 0; n < 4; ++n) {
            tm = fmaxf(tm, fmaxf(fmaxf(acc[n][0], acc[n][1]), fmaxf(acc[n][2], acc[n][3])));
        }
        tm = fmaxf(tm, __shfl_xor(tm, 16, 64));
        tm = fmaxf(tm, __shfl_xor(tm, 32, 64));
        float mnew = fmaxf(m, tm);
        float scale = __expf(m - mnew);
        float ts = 0.f;
        #pragma unroll
        for (int n = 0; n < 4; ++n)
            #pragma unroll
            for (int r = 0; r < 4; ++r) {
                float p = __expf(acc[n][r] - mnew);
                acc[n][r] = p;
                ts += p;
            }
        ts += __shfl_xor(ts, 16, 64);
        ts += __shfl_xor(ts, 32, 64);
        l = l * scale + ts;
        m = mnew;
        #pragma unroll
        for (int n = 0; n < 4; ++n) o[n] = o[n] * scale;

        // P -> per-wave LDS (C layout -> [q][j] bf16), then PV B-frags
        #pragma unroll
        for (int n = 0; n < 4; ++n) {
            ushort4 u;
            u.x = f2bf(acc[n][0]); u.y = f2bf(acc[n][1]);
            u.z = f2bf(acc[n][2]); u.w = f2bf(acc[n][3]);
            *(ushort4*)&P_lds[wave][lq][16 * n + lg * 4] = u;
        }
        bf16x8 bp0 = *(const bf16x8*)&P_lds[wave][lq][lg * 8];
        bf16x8 bp1 = *(const bf16x8*)&P_lds[wave][lq][32 + lg * 8];

        // O^T += V^T @ P^T
        const unsigned short* vbase = vt + (size_t)bh * DD * SS + jbase + lg * 8;
        #pragma unroll
        for (int n = 0; n < 4; ++n) {
            const unsigned short* vr0 = vbase + (size_t)(16 * n + lq) * SS;
            o[n] = __builtin_amdgcn_mfma_f32_16x16x32_bf16(
                *(const bf16x8*)vr0, bp0, o[n], 0, 0, 0);
            o[n] = __builtin_amdgcn_mfma_f32_16x16x32_bf16(
                *(const bf16x8*)(vr0 + 32), bp1, o[n], 0, 0, 0);
        }
    }

    float g = gi / l;
    #pragma unroll
    for (int n = 0; n < 4; ++n) {
        ushort4 u;
        u.x = f2bf(o[n][0] * g); u.y = f2bf(o[n][1] * g);
        u.z = f2bf(o[n][2] * g); u.w = f2bf(o[n][3] * g);
        *(ushort4*)(ao + (((size_t)b * SS + i) * HH + h) * DD + 16 * n + lg * 4) = u;
    }
}

// ------------------------------------------------------------------
extern "C" void kernel_launch(void* const* d_in, const int* in_sizes, int n_in,
                              void* d_out, int out_size, void* d_ws, size_t ws_size,
                              hipStream_t stream)
{
    const float* tokens = (const float*)d_in[0];
    const float* vres   = (const float*)d_in[1];
    const int*   ep     = (const int*)d_in[2];
    const float* Wq     = (const float*)d_in[3];
    const float* Wkv    = (const float*)d_in[4];
    const float* Wo     = (const float*)d_in[5];
    const float* Wg     = (const float*)d_in[6];
    const float* Wmix   = (const float*)d_in[7];
    float* out = (float*)d_out;

    char* wsb = (char*)d_ws;
    unsigned short* qbh  = (unsigned short*)(wsb + 0);         // 8 MB
    unsigned short* kbh  = (unsigned short*)(wsb + 8388608);   // 8 MB
    unsigned short* vb0  = (unsigned short*)(wsb + 16777216);  // 8 MB
    unsigned short* vtb  = (unsigned short*)(wsb + 25165824);  // 8 MB
    unsigned short* aob  = (unsigned short*)(wsb + 33554432);  // 8 MB
    unsigned short* tokA = (unsigned short*)(wsb + 41943040);  // 8 MB
    unsigned short* BtW  = (unsigned short*)(wsb + 50331648);  // 6 MB
    unsigned short* WotW = BtW;                                 // alias (after proj)
    float* gatep = (float*)(wsb + 56623104);                   // 256 KB
    float* mixp  = (float*)(wsb + 56885248);                   // 256 KB
    int*   epst  = (int*)(wsb + 57147392);                     // 16 KB

    cvt_bf16_kernel<<<2048, 256, 0, stream>>>(tokens, tokA, (BB * SS * DIMM) / 4);
    transpose_cvt_kernel<<<dim3(32, 32), dim3(32, 8), 0, stream>>>(Wq,  BtW,               1024, 1024);
    transpose_cvt_kernel<<<dim3(64, 32), dim3(32, 8), 0, stream>>>(Wkv, BtW + 1024 * 1024, 1024, 2048);
    mixgate_kernel<<<BB * SS, 256, 0, stream>>>(tokens, Wg, Wmix, gatep, mixp);
    epstart_kernel<<<16, 256, 0, stream>>>(ep, epst);

    gemm_mfma<1><<<dim3(24, 32), 256, 0, stream>>>(tokA, BtW, qbh, kbh, vb0);
    rope_lerp_kernel<<<dim3(SS / 64, BB * HH), 256, 0, stream>>>(qbh, kbh, vb0, vres, mixp, vtb);
    attn_mfma<<<dim3(SS / 64, BB * HH), 256, 0, stream>>>(qbh, kbh, vtb, epst, gatep, aob);

    transpose_cvt_kernel<<<dim3(32, 32), dim3(32, 8), 0, stream>>>(Wo, WotW, 1024, 1024);
    gemm_mfma<0><<<dim3(8, 32), 256, 0, stream>>>(aob, WotW, out, nullptr, nullptr);
}

// Round 5
// 171.197 us; speedup vs baseline: 12.8000x; 1.6524x over previous
//
#include <hip/hip_runtime.h>
#include <math.h>

#define BB 2
#define SS 2048
#define DIMM 1024
#define HH 16
#define DD 64
#define WINDOW 512

typedef __bf16 bf16x8 __attribute__((ext_vector_type(8)));
typedef float f32x4 __attribute__((ext_vector_type(4)));

__device__ __forceinline__ unsigned short f2bf(float f) {
    unsigned int u = __float_as_uint(f);
    u = (u + 0x7FFFu + ((u >> 16) & 1u)) >> 16;
    return (unsigned short)u;
}
__device__ __forceinline__ float bf2f(unsigned short u) {
    return __uint_as_float((unsigned int)u << 16);
}

__device__ __forceinline__ void async_cp16(unsigned short* lds_dst, const unsigned short* g_src) {
    __builtin_amdgcn_global_load_lds(
        (const __attribute__((address_space(1))) unsigned int*)g_src,
        (__attribute__((address_space(3))) unsigned int*)lds_dst, 16, 0, 0);
}

// ------------------------------------------------------------------
// fp32 -> bf16 flat convert (tokens)
// ------------------------------------------------------------------
__global__ __launch_bounds__(256) void cvt_bf16_kernel(
    const float* __restrict__ src, unsigned short* __restrict__ dst, int n4)
{
    for (int i = blockIdx.x * 256 + threadIdx.x; i < n4; i += gridDim.x * 256) {
        float4 v = ((const float4*)src)[i];
        ushort4 o;
        o.x = f2bf(v.x); o.y = f2bf(v.y); o.z = f2bf(v.z); o.w = f2bf(v.w);
        ((ushort4*)dst)[i] = o;
    }
}

// ------------------------------------------------------------------
// transpose + convert: src fp32 [R][C] -> dst bf16 [C][R]
// ------------------------------------------------------------------
__global__ __launch_bounds__(256) void transpose_cvt_kernel(
    const float* __restrict__ src, unsigned short* __restrict__ dst, int R, int C)
{
    __shared__ float t[32][33];
    int c0 = blockIdx.x * 32, r0 = blockIdx.y * 32;
    int tx = threadIdx.x, ty = threadIdx.y;
    #pragma unroll
    for (int u = 0; u < 4; ++u)
        t[ty + 8 * u][tx] = src[(size_t)(r0 + ty + 8 * u) * C + c0 + tx];
    __syncthreads();
    #pragma unroll
    for (int u = 0; u < 4; ++u)
        dst[(size_t)(c0 + ty + 8 * u) * R + r0 + tx] = f2bf(t[tx][ty + 8 * u]);
}

// ------------------------------------------------------------------
// pack [Wg|Wmix] (each [1024][16] fp32) -> N-major bf16 [32][1024]
// ------------------------------------------------------------------
__global__ __launch_bounds__(256) void build_wgmt_kernel(
    const float* __restrict__ Wg, const float* __restrict__ Wmix,
    unsigned short* __restrict__ dst)
{
    int idx = blockIdx.x * 256 + threadIdx.x;   // 0..32767
    int n = idx >> 10, k = idx & 1023;
    const float* src = (n < 16) ? Wg : Wmix;
    dst[idx] = f2bf(src[k * HH + (n & 15)]);
}

// ------------------------------------------------------------------
// mix & gate via MFMA: sigmoid(tokens_bf16 @ Wgm^T), N=32
// grid 128 blocks x 32 rows; 4 waves K-split (256 each); LDS reduce
// ------------------------------------------------------------------
__global__ __launch_bounds__(256) void mixgate_mfma(
    const unsigned short* __restrict__ A,      // [4096][1024] bf16
    const unsigned short* __restrict__ Bt,     // [32][1024] bf16
    float* __restrict__ gate, float* __restrict__ mix)
{
    int mbase = blockIdx.x * 32;
    int tid = threadIdx.x;
    int wave = tid >> 6, lane = tid & 63;
    int fr = lane & 15, hi = lane >> 4;
    int kw = wave * 256;

    __shared__ float red[4][32][32];

    f32x4 acc[2][2];
    #pragma unroll
    for (int m_ = 0; m_ < 2; ++m_)
        #pragma unroll
        for (int n_ = 0; n_ < 2; ++n_)
            acc[m_][n_] = (f32x4){0.f, 0.f, 0.f, 0.f};

    const unsigned short* a0 = A + (size_t)(mbase + fr) * 1024 + kw + hi * 8;
    const unsigned short* a1 = A + (size_t)(mbase + 16 + fr) * 1024 + kw + hi * 8;
    const unsigned short* b0 = Bt + (size_t)fr * 1024 + kw + hi * 8;
    const unsigned short* b1 = Bt + (size_t)(16 + fr) * 1024 + kw + hi * 8;

    #pragma unroll 2
    for (int k = 0; k < 256; k += 32) {
        bf16x8 af0 = *(const bf16x8*)(a0 + k);
        bf16x8 af1 = *(const bf16x8*)(a1 + k);
        bf16x8 bf0 = *(const bf16x8*)(b0 + k);
        bf16x8 bf1 = *(const bf16x8*)(b1 + k);
        acc[0][0] = __builtin_amdgcn_mfma_f32_16x16x32_bf16(af0, bf0, acc[0][0], 0, 0, 0);
        acc[0][1] = __builtin_amdgcn_mfma_f32_16x16x32_bf16(af0, bf1, acc[0][1], 0, 0, 0);
        acc[1][0] = __builtin_amdgcn_mfma_f32_16x16x32_bf16(af1, bf0, acc[1][0], 0, 0, 0);
        acc[1][1] = __builtin_amdgcn_mfma_f32_16x16x32_bf16(af1, bf1, acc[1][1], 0, 0, 0);
    }

    #pragma unroll
    for (int m_ = 0; m_ < 2; ++m_)
        #pragma unroll
        for (int n_ = 0; n_ < 2; ++n_)
            #pragma unroll
            for (int j = 0; j < 4; ++j)
                red[wave][m_ * 16 + hi * 4 + j][n_ * 16 + fr] = acc[m_][n_][j];
    __syncthreads();

    #pragma unroll
    for (int e = 0; e < 4; ++e) {
        int idx = (tid << 2) | e;          // 0..1023
        int r = idx >> 5, c = idx & 31;
        float s4 = red[0][r][c] + red[1][r][c] + red[2][r][c] + red[3][r][c];
        float sg = 1.f / (1.f + __expf(-s4));
        int mg = mbase + r;
        int b = mg >> 11, s = mg & 2047;
        int h = c & 15;
        float* dst = (c < 16) ? gate : mix;
        dst[((size_t)b * HH + h) * SS + s] = sg;
    }
}

// ------------------------------------------------------------------
// episode start: epstart[b][i] = first index of i's episode (sorted ids)
// ------------------------------------------------------------------
__global__ __launch_bounds__(256) void epstart_kernel(
    const int* __restrict__ ep, int* __restrict__ epstart)
{
    int idx = blockIdx.x * 256 + threadIdx.x;   // b*S + i
    int b = idx >> 11, i = idx & 2047;
    const int* e = ep + b * SS;
    int v = e[i];
    int lo = 0, hi = i;
    while (lo < hi) {
        int mid = (lo + hi) >> 1;
        if (e[mid] == v) hi = mid; else lo = mid + 1;
    }
    epstart[idx] = lo;
}

// ------------------------------------------------------------------
// bf16 MFMA GEMM: A [M][1024] bf16 row-major, Bt [N][1024] bf16 (N-major)
// EPI=0: C fp32 [M][1024]; EPI=1: scatter bf16 q/k/v (B,H,S,D)
// ------------------------------------------------------------------
template<int EPI>
__global__ __launch_bounds__(256) void gemm_mfma(
    const unsigned short* __restrict__ A, const unsigned short* __restrict__ Bt,
    void* __restrict__ o0v, void* __restrict__ o1v, void* __restrict__ o2v)
{
    const int K = 1024;
    int nbase = blockIdx.x * 128;
    int mbase = blockIdx.y * 128;
    int tid = threadIdx.x;
    int lane = tid & 63;
    int wave = tid >> 6;
    int wr = wave >> 1, wc = wave & 1;
    int fr = lane & 15, hi = lane >> 4;

    __shared__ unsigned short As[128 * 32];
    __shared__ unsigned short Bs[128 * 32];

    int srow = tid >> 2;
    int sp   = tid & 3;
    int scol = (sp ^ ((srow >> 1) & 3)) * 8;
    const unsigned short* agp0 = A  + (size_t)(mbase + srow) * K + scol;
    const unsigned short* agp1 = A  + (size_t)(mbase + srow + 64) * K + scol;
    const unsigned short* bgp0 = Bt + (size_t)(nbase + srow) * K + scol;
    const unsigned short* bgp1 = Bt + (size_t)(nbase + srow + 64) * K + scol;
    unsigned short* al0 = &As[tid * 8];
    unsigned short* al1 = &As[2048 + tid * 8];
    unsigned short* bl0 = &Bs[tid * 8];
    unsigned short* bl1 = &Bs[2048 + tid * 8];

    f32x4 acc[4][4];
    #pragma unroll
    for (int m_ = 0; m_ < 4; ++m_)
        #pragma unroll
        for (int n_ = 0; n_ < 4; ++n_)
            acc[m_][n_] = (f32x4){0.f, 0.f, 0.f, 0.f};

    int aidx[4], bidx[4];
    #pragma unroll
    for (int m_ = 0; m_ < 4; ++m_) {
        int row = wr * 64 + m_ * 16 + fr;
        aidx[m_] = row * 32 + (hi ^ ((row >> 1) & 3)) * 8;
    }
    #pragma unroll
    for (int n_ = 0; n_ < 4; ++n_) {
        int row = wc * 64 + n_ * 16 + fr;
        bidx[n_] = row * 32 + (hi ^ ((row >> 1) & 3)) * 8;
    }

    for (int k0 = 0; k0 < K; k0 += 32) {
        __syncthreads();
        async_cp16(al0, agp0 + k0);
        async_cp16(al1, agp1 + k0);
        async_cp16(bl0, bgp0 + k0);
        async_cp16(bl1, bgp1 + k0);
        __syncthreads();

        bf16x8 af[4], bfr[4];
        #pragma unroll
        for (int m_ = 0; m_ < 4; ++m_) af[m_] = *(const bf16x8*)&As[aidx[m_]];
        #pragma unroll
        for (int n_ = 0; n_ < 4; ++n_) bfr[n_] = *(const bf16x8*)&Bs[bidx[n_]];
        #pragma unroll
        for (int m_ = 0; m_ < 4; ++m_)
            #pragma unroll
            for (int n_ = 0; n_ < 4; ++n_)
                acc[m_][n_] = __builtin_amdgcn_mfma_f32_16x16x32_bf16(
                    af[m_], bfr[n_], acc[m_][n_], 0, 0, 0);
    }

    #pragma unroll
    for (int m_ = 0; m_ < 4; ++m_) {
        #pragma unroll
        for (int n_ = 0; n_ < 4; ++n_) {
            int c = nbase + wc * 64 + n_ * 16 + fr;
            #pragma unroll
            for (int j = 0; j < 4; ++j) {
                int mg = mbase + wr * 64 + m_ * 16 + hi * 4 + j;
                float v = acc[m_][n_][j];
                if (EPI == 0) {
                    ((float*)o0v)[(size_t)mg * 1024 + c] = v;
                } else {
                    int b = mg >> 11, s = mg & 2047;
                    int cc = c & 1023, h = cc >> 6, d = cc & 63;
                    unsigned short* dst = (c < 1024) ? (unsigned short*)o0v
                                        : (c < 2048) ? (unsigned short*)o1v
                                                     : (unsigned short*)o2v;
                    dst[(((size_t)b * HH + h) * SS + s) * DD + d] = f2bf(v);
                }
            }
        }
    }
}

// ------------------------------------------------------------------
// RoPE in-place on bf16 q,k; V lerp -> V^T bf16 [bh][d][s]
// ------------------------------------------------------------------
__global__ __launch_bounds__(256) void rope_lerp_kernel(
    unsigned short* __restrict__ q, unsigned short* __restrict__ k,
    const unsigned short* __restrict__ v0, const float* __restrict__ vres,
    const float* __restrict__ mix, unsigned short* __restrict__ vt)
{
    int st = blockIdx.x;
    int bh = blockIdx.y;
    int tid = threadIdx.x;
    int sl = tid >> 2;
    int dg = (tid & 3) * 16;
    int s = st * 64 + sl;
    size_t rowoff = ((size_t)bh * SS + s) * DD + dg;

    __shared__ unsigned short vtile[64][66];

    union { uint4 v[2]; unsigned short u[16]; } qa, ka, va;
    qa.v[0] = *(const uint4*)(q + rowoff);
    qa.v[1] = *(const uint4*)(q + rowoff + 8);
    ka.v[0] = *(const uint4*)(k + rowoff);
    ka.v[1] = *(const uint4*)(k + rowoff + 8);
    va.v[0] = *(const uint4*)(v0 + rowoff);
    va.v[1] = *(const uint4*)(v0 + rowoff + 8);
    float4 w[4];
    #pragma unroll
    for (int u = 0; u < 4; ++u) w[u] = *(const float4*)(vres + rowoff + 4 * u);
    float mx = mix[(size_t)bh * SS + s];

    #pragma unroll
    for (int u = 0; u < 8; ++u) {
        int d0 = dg + 2 * u;
        float inv_freq = powf(10000.f, -(float)d0 * (1.f / 64.f));
        float fr = (float)s * inv_freq;
        float red = fr - 6.2831853f * floorf(fr * 0.15915494f);
        float cs, sn;
        __sincosf(red, &sn, &cs);
        float x = bf2f(qa.u[2 * u]), y = bf2f(qa.u[2 * u + 1]);
        qa.u[2 * u]     = f2bf((x * cs - y * sn) * 0.125f);
        qa.u[2 * u + 1] = f2bf((y * cs + x * sn) * 0.125f);
        x = bf2f(ka.u[2 * u]); y = bf2f(ka.u[2 * u + 1]);
        ka.u[2 * u]     = f2bf(x * cs - y * sn);
        ka.u[2 * u + 1] = f2bf(y * cs + x * sn);
    }
    *(uint4*)(q + rowoff)     = qa.v[0];
    *(uint4*)(q + rowoff + 8) = qa.v[1];
    *(uint4*)(k + rowoff)     = ka.v[0];
    *(uint4*)(k + rowoff + 8) = ka.v[1];

    #pragma unroll
    for (int e = 0; e < 16; ++e) {
        float vv = bf2f(va.u[e]);
        float wr = ((const float*)w)[e];
        vtile[sl][dg + e] = f2bf(vv + mx * (wr - vv));
    }
    __syncthreads();

    int d = tid >> 2;
    int sseg = (tid & 3) * 16;
    union { uint4 v[2]; unsigned short u[16]; } ot;
    #pragma unroll
    for (int e = 0; e < 16; ++e) ot.u[e] = vtile[sseg + e][d];
    unsigned short* dst = vt + ((size_t)bh * DD + d) * SS + st * 64 + sseg;
    *(uint4*)dst = ot.v[0];
    *(uint4*)(dst + 8) = ot.v[1];
}

// ------------------------------------------------------------------
// MFMA flash attention (swapped operands), 4 waves x 16 queries
// ------------------------------------------------------------------
__global__ __launch_bounds__(256) void attn_mfma(
    const unsigned short* __restrict__ qbh, const unsigned short* __restrict__ kbh,
    const unsigned short* __restrict__ vt, const int* __restrict__ epstart,
    const float* __restrict__ gate, unsigned short* __restrict__ ao)
{
    int qt = blockIdx.x, bh = blockIdx.y;
    int b = bh >> 4, h = bh & 15;
    int q0 = qt * 64;
    int tid = threadIdx.x;
    int wave = tid >> 6, lane = tid & 63;
    int lq = lane & 15, lg = lane >> 4;
    int i = q0 + wave * 16 + lq;

    alignas(16) __shared__ unsigned short P_lds[4][16][72];

    const unsigned short* qrow = qbh + ((size_t)bh * SS + i) * DD + lg * 8;
    bf16x8 bq0 = *(const bf16x8*)qrow;
    bf16x8 bq1 = *(const bf16x8*)(qrow + 32);

    int jmin = i - WINDOW;
    int es = epstart[b * SS + i];
    if (es > jmin) jmin = es;
    float gi = gate[(size_t)bh * SS + i];

    float m = -1e30f, l = 0.f;
    f32x4 o[4];
    #pragma unroll
    for (int n = 0; n < 4; ++n) o[n] = (f32x4){0.f, 0.f, 0.f, 0.f};

    int t0 = (qt < 8) ? (8 - qt) : 0;
    for (int t = t0; t < 9; ++t) {
        int jbase = 64 * (qt - 8 + t);

        f32x4 acc[4];
        #pragma unroll
        for (int n = 0; n < 4; ++n) acc[n] = (f32x4){0.f, 0.f, 0.f, 0.f};
        const unsigned short* kbase = kbh + ((size_t)bh * SS + jbase) * DD + lg * 8;
        #pragma unroll
        for (int n = 0; n < 4; ++n) {
            const unsigned short* kr = kbase + (size_t)(16 * n + lq) * DD;
            acc[n] = __builtin_amdgcn_mfma_f32_16x16x32_bf16(
                *(const bf16x8*)kr, bq0, acc[n], 0, 0, 0);
            acc[n] = __builtin_amdgcn_mfma_f32_16x16x32_bf16(
                *(const bf16x8*)(kr + 32), bq1, acc[n], 0, 0, 0);
        }

        int jb = jbase + lg * 4;
        #pragma unroll
        for (int n = 0; n < 4; ++n)
            #pragma unroll
            for (int r = 0; r < 4; ++r) {
                int j = jb + 16 * n + r;
                if (j < jmin || j > i) acc[n][r] = -3e38f;
            }

        float tm = -3e38f;
        #pragma unroll
        for (int n = 0; n < 4; ++n) {
            tm = fmaxf(tm, fmaxf(fmaxf(acc[n][0], acc[n][1]), fmaxf(acc[n][2], acc[n][3])));
        }
        tm = fmaxf(tm, __shfl_xor(tm, 16, 64));
        tm = fmaxf(tm, __shfl_xor(tm, 32, 64));
        float mnew = fmaxf(m, tm);
        float scale = __expf(m - mnew);
        float ts = 0.f;
        #pragma unroll
        for (int n = 0; n < 4; ++n)
            #pragma unroll
            for (int r = 0; r < 4; ++r) {
                float p = __expf(acc[n][r] - mnew);
                acc[n][r] = p;
                ts += p;
            }
        ts += __shfl_xor(ts, 16, 64);
        ts += __shfl_xor(ts, 32, 64);
        l = l * scale + ts;
        m = mnew;
        #pragma unroll
        for (int n = 0; n < 4; ++n) o[n] = o[n] * scale;

        #pragma unroll
        for (int n = 0; n < 4; ++n) {
            ushort4 u;
            u.x = f2bf(acc[n][0]); u.y = f2bf(acc[n][1]);
            u.z = f2bf(acc[n][2]); u.w = f2bf(acc[n][3]);
            *(ushort4*)&P_lds[wave][lq][16 * n + lg * 4] = u;
        }
        bf16x8 bp0 = *(const bf16x8*)&P_lds[wave][lq][lg * 8];
        bf16x8 bp1 = *(const bf16x8*)&P_lds[wave][lq][32 + lg * 8];

        const unsigned short* vbase = vt + (size_t)bh * DD * SS + jbase + lg * 8;
        #pragma unroll
        for (int n = 0; n < 4; ++n) {
            const unsigned short* vr0 = vbase + (size_t)(16 * n + lq) * SS;
            o[n] = __builtin_amdgcn_mfma_f32_16x16x32_bf16(
                *(const bf16x8*)vr0, bp0, o[n], 0, 0, 0);
            o[n] = __builtin_amdgcn_mfma_f32_16x16x32_bf16(
                *(const bf16x8*)(vr0 + 32), bp1, o[n], 0, 0, 0);
        }
    }

    float g = gi / l;
    #pragma unroll
    for (int n = 0; n < 4; ++n) {
        ushort4 u;
        u.x = f2bf(o[n][0] * g); u.y = f2bf(o[n][1] * g);
        u.z = f2bf(o[n][2] * g); u.w = f2bf(o[n][3] * g);
        *(ushort4*)(ao + (((size_t)b * SS + i) * HH + h) * DD + 16 * n + lg * 4) = u;
    }
}

// ------------------------------------------------------------------
extern "C" void kernel_launch(void* const* d_in, const int* in_sizes, int n_in,
                              void* d_out, int out_size, void* d_ws, size_t ws_size,
                              hipStream_t stream)
{
    const float* tokens = (const float*)d_in[0];
    const float* vres   = (const float*)d_in[1];
    const int*   ep     = (const int*)d_in[2];
    const float* Wq     = (const float*)d_in[3];
    const float* Wkv    = (const float*)d_in[4];
    const float* Wo     = (const float*)d_in[5];
    const float* Wg     = (const float*)d_in[6];
    const float* Wmix   = (const float*)d_in[7];
    float* out = (float*)d_out;

    char* wsb = (char*)d_ws;
    unsigned short* qbh  = (unsigned short*)(wsb + 0);         // 8 MB
    unsigned short* kbh  = (unsigned short*)(wsb + 8388608);   // 8 MB
    unsigned short* vb0  = (unsigned short*)(wsb + 16777216);  // 8 MB
    unsigned short* vtb  = (unsigned short*)(wsb + 25165824);  // 8 MB
    unsigned short* aob  = (unsigned short*)(wsb + 33554432);  // 8 MB
    unsigned short* tokA = (unsigned short*)(wsb + 41943040);  // 8 MB
    unsigned short* BtW  = (unsigned short*)(wsb + 50331648);  // 6 MB
    unsigned short* WotW = BtW;                                 // alias (after proj)
    float* gatep = (float*)(wsb + 56623104);                   // 256 KB
    float* mixp  = (float*)(wsb + 56885248);                   // 256 KB
    int*   epst  = (int*)(wsb + 57147392);                     // 16 KB
    unsigned short* wgmt = (unsigned short*)(wsb + 57163776);  // 64 KB

    cvt_bf16_kernel<<<2048, 256, 0, stream>>>(tokens, tokA, (BB * SS * DIMM) / 4);
    transpose_cvt_kernel<<<dim3(32, 32), dim3(32, 8), 0, stream>>>(Wq,  BtW,               1024, 1024);
    transpose_cvt_kernel<<<dim3(64, 32), dim3(32, 8), 0, stream>>>(Wkv, BtW + 1024 * 1024, 1024, 2048);
    build_wgmt_kernel<<<128, 256, 0, stream>>>(Wg, Wmix, wgmt);
    epstart_kernel<<<16, 256, 0, stream>>>(ep, epst);

    mixgate_mfma<<<128, 256, 0, stream>>>(tokA, wgmt, gatep, mixp);
    gemm_mfma<1><<<dim3(24, 32), 256, 0, stream>>>(tokA, BtW, qbh, kbh, vb0);
    rope_lerp_kernel<<<dim3(SS / 64, BB * HH), 256, 0, stream>>>(qbh, kbh, vb0, vres, mixp, vtb);
    attn_mfma<<<dim3(SS / 64, BB * HH), 256, 0, stream>>>(qbh, kbh, vtb, epst, gatep, aob);

    transpose_cvt_kernel<<<dim3(32, 32), dim3(32, 8), 0, stream>>>(Wo, WotW, 1024, 1024);
    gemm_mfma<0><<<dim3(8, 32), 256, 0, stream>>>(aob, WotW, out, nullptr, nullptr);
}

// Round 6
// 132.072 us; speedup vs baseline: 16.5918x; 1.2962x over previous
//
#include <hip/hip_runtime.h>
#include <math.h>

#define BB 2
#define SS 2048
#define DIMM 1024
#define HH 16
#define DD 64
#define WINDOW 512

typedef __bf16 bf16x8 __attribute__((ext_vector_type(8)));
typedef float f32x4 __attribute__((ext_vector_type(4)));

__device__ __forceinline__ unsigned short f2bf(float f) {
    unsigned int u = __float_as_uint(f);
    u = (u + 0x7FFFu + ((u >> 16) & 1u)) >> 16;
    return (unsigned short)u;
}
__device__ __forceinline__ float bf2f(unsigned short u) {
    return __uint_as_float((unsigned int)u << 16);
}

__device__ __forceinline__ void async_cp16(unsigned short* lds_dst, const unsigned short* g_src) {
    __builtin_amdgcn_global_load_lds(
        (const __attribute__((address_space(1))) unsigned int*)g_src,
        (__attribute__((address_space(3))) unsigned int*)lds_dst, 16, 0, 0);
}

// ------------------------------------------------------------------
// fp32 -> bf16 flat convert (tokens)
// ------------------------------------------------------------------
__global__ __launch_bounds__(256) void cvt_bf16_kernel(
    const float* __restrict__ src, unsigned short* __restrict__ dst, int n4)
{
    for (int i = blockIdx.x * 256 + threadIdx.x; i < n4; i += gridDim.x * 256) {
        float4 v = ((const float4*)src)[i];
        ushort4 o;
        o.x = f2bf(v.x); o.y = f2bf(v.y); o.z = f2bf(v.z); o.w = f2bf(v.w);
        ((ushort4*)dst)[i] = o;
    }
}

// ------------------------------------------------------------------
// transpose + convert: src fp32 [R][C] -> dst bf16 [C][R]
// ------------------------------------------------------------------
__global__ __launch_bounds__(256) void transpose_cvt_kernel(
    const float* __restrict__ src, unsigned short* __restrict__ dst, int R, int C)
{
    __shared__ float t[32][33];
    int c0 = blockIdx.x * 32, r0 = blockIdx.y * 32;
    int tx = threadIdx.x, ty = threadIdx.y;
    #pragma unroll
    for (int u = 0; u < 4; ++u)
        t[ty + 8 * u][tx] = src[(size_t)(r0 + ty + 8 * u) * C + c0 + tx];
    __syncthreads();
    #pragma unroll
    for (int u = 0; u < 4; ++u)
        dst[(size_t)(c0 + ty + 8 * u) * R + r0 + tx] = f2bf(t[tx][ty + 8 * u]);
}

// ------------------------------------------------------------------
// pack [Wg|Wmix] (each [1024][16] fp32) -> N-major bf16 [32][1024]
// ------------------------------------------------------------------
__global__ __launch_bounds__(256) void build_wgmt_kernel(
    const float* __restrict__ Wg, const float* __restrict__ Wmix,
    unsigned short* __restrict__ dst)
{
    int idx = blockIdx.x * 256 + threadIdx.x;   // 0..32767
    int n = idx >> 10, k = idx & 1023;
    const float* src = (n < 16) ? Wg : Wmix;
    dst[idx] = f2bf(src[k * HH + (n & 15)]);
}

// ------------------------------------------------------------------
// mix & gate via MFMA: sigmoid(tokens_bf16 @ Wgm^T), N=32
// ------------------------------------------------------------------
__global__ __launch_bounds__(256) void mixgate_mfma(
    const unsigned short* __restrict__ A,      // [4096][1024] bf16
    const unsigned short* __restrict__ Bt,     // [32][1024] bf16
    float* __restrict__ gate, float* __restrict__ mix)
{
    int mbase = blockIdx.x * 32;
    int tid = threadIdx.x;
    int wave = tid >> 6, lane = tid & 63;
    int fr = lane & 15, hi = lane >> 4;
    int kw = wave * 256;

    __shared__ float red[4][32][32];

    f32x4 acc[2][2];
    #pragma unroll
    for (int m_ = 0; m_ < 2; ++m_)
        #pragma unroll
        for (int n_ = 0; n_ < 2; ++n_)
            acc[m_][n_] = (f32x4){0.f, 0.f, 0.f, 0.f};

    const unsigned short* a0 = A + (size_t)(mbase + fr) * 1024 + kw + hi * 8;
    const unsigned short* a1 = A + (size_t)(mbase + 16 + fr) * 1024 + kw + hi * 8;
    const unsigned short* b0 = Bt + (size_t)fr * 1024 + kw + hi * 8;
    const unsigned short* b1 = Bt + (size_t)(16 + fr) * 1024 + kw + hi * 8;

    #pragma unroll 2
    for (int k = 0; k < 256; k += 32) {
        bf16x8 af0 = *(const bf16x8*)(a0 + k);
        bf16x8 af1 = *(const bf16x8*)(a1 + k);
        bf16x8 bf0 = *(const bf16x8*)(b0 + k);
        bf16x8 bf1 = *(const bf16x8*)(b1 + k);
        acc[0][0] = __builtin_amdgcn_mfma_f32_16x16x32_bf16(af0, bf0, acc[0][0], 0, 0, 0);
        acc[0][1] = __builtin_amdgcn_mfma_f32_16x16x32_bf16(af0, bf1, acc[0][1], 0, 0, 0);
        acc[1][0] = __builtin_amdgcn_mfma_f32_16x16x32_bf16(af1, bf0, acc[1][0], 0, 0, 0);
        acc[1][1] = __builtin_amdgcn_mfma_f32_16x16x32_bf16(af1, bf1, acc[1][1], 0, 0, 0);
    }

    #pragma unroll
    for (int m_ = 0; m_ < 2; ++m_)
        #pragma unroll
        for (int n_ = 0; n_ < 2; ++n_)
            #pragma unroll
            for (int j = 0; j < 4; ++j)
                red[wave][m_ * 16 + hi * 4 + j][n_ * 16 + fr] = acc[m_][n_][j];
    __syncthreads();

    #pragma unroll
    for (int e = 0; e < 4; ++e) {
        int idx = (tid << 2) | e;          // 0..1023
        int r = idx >> 5, c = idx & 31;
        float s4 = red[0][r][c] + red[1][r][c] + red[2][r][c] + red[3][r][c];
        float sg = 1.f / (1.f + __expf(-s4));
        int mg = mbase + r;
        int b = mg >> 11, s = mg & 2047;
        int h = c & 15;
        float* dst = (c < 16) ? gate : mix;
        dst[((size_t)b * HH + h) * SS + s] = sg;
    }
}

// ------------------------------------------------------------------
// episode start: epstart[b][i] = first index of i's episode (sorted ids)
// ------------------------------------------------------------------
__global__ __launch_bounds__(256) void epstart_kernel(
    const int* __restrict__ ep, int* __restrict__ epstart)
{
    int idx = blockIdx.x * 256 + threadIdx.x;   // b*S + i
    int b = idx >> 11, i = idx & 2047;
    const int* e = ep + b * SS;
    int v = e[i];
    int lo = 0, hi = i;
    while (lo < hi) {
        int mid = (lo + hi) >> 1;
        if (e[mid] == v) hi = mid; else lo = mid + 1;
    }
    epstart[idx] = lo;
}

// ------------------------------------------------------------------
// bf16 MFMA GEMM: A [M][1024] bf16 row-major, Bt [N][1024] bf16 (N-major)
// EPI=0: C fp32 [M][1024]; EPI=1: scatter bf16 q/k/v (B,H,S,D)
// ------------------------------------------------------------------
template<int EPI>
__global__ __launch_bounds__(256) void gemm_mfma(
    const unsigned short* __restrict__ A, const unsigned short* __restrict__ Bt,
    void* __restrict__ o0v, void* __restrict__ o1v, void* __restrict__ o2v)
{
    const int K = 1024;
    int nbase = blockIdx.x * 128;
    int mbase = blockIdx.y * 128;
    int tid = threadIdx.x;
    int lane = tid & 63;
    int wave = tid >> 6;
    int wr = wave >> 1, wc = wave & 1;
    int fr = lane & 15, hi = lane >> 4;

    __shared__ unsigned short As[128 * 32];
    __shared__ unsigned short Bs[128 * 32];

    int srow = tid >> 2;
    int sp   = tid & 3;
    int scol = (sp ^ ((srow >> 1) & 3)) * 8;
    const unsigned short* agp0 = A  + (size_t)(mbase + srow) * K + scol;
    const unsigned short* agp1 = A  + (size_t)(mbase + srow + 64) * K + scol;
    const unsigned short* bgp0 = Bt + (size_t)(nbase + srow) * K + scol;
    const unsigned short* bgp1 = Bt + (size_t)(nbase + srow + 64) * K + scol;
    unsigned short* al0 = &As[tid * 8];
    unsigned short* al1 = &As[2048 + tid * 8];
    unsigned short* bl0 = &Bs[tid * 8];
    unsigned short* bl1 = &Bs[2048 + tid * 8];

    f32x4 acc[4][4];
    #pragma unroll
    for (int m_ = 0; m_ < 4; ++m_)
        #pragma unroll
        for (int n_ = 0; n_ < 4; ++n_)
            acc[m_][n_] = (f32x4){0.f, 0.f, 0.f, 0.f};

    int aidx[4], bidx[4];
    #pragma unroll
    for (int m_ = 0; m_ < 4; ++m_) {
        int row = wr * 64 + m_ * 16 + fr;
        aidx[m_] = row * 32 + (hi ^ ((row >> 1) & 3)) * 8;
    }
    #pragma unroll
    for (int n_ = 0; n_ < 4; ++n_) {
        int row = wc * 64 + n_ * 16 + fr;
        bidx[n_] = row * 32 + (hi ^ ((row >> 1) & 3)) * 8;
    }

    for (int k0 = 0; k0 < K; k0 += 32) {
        __syncthreads();
        async_cp16(al0, agp0 + k0);
        async_cp16(al1, agp1 + k0);
        async_cp16(bl0, bgp0 + k0);
        async_cp16(bl1, bgp1 + k0);
        __syncthreads();

        bf16x8 af[4], bfr[4];
        #pragma unroll
        for (int m_ = 0; m_ < 4; ++m_) af[m_] = *(const bf16x8*)&As[aidx[m_]];
        #pragma unroll
        for (int n_ = 0; n_ < 4; ++n_) bfr[n_] = *(const bf16x8*)&Bs[bidx[n_]];
        #pragma unroll
        for (int m_ = 0; m_ < 4; ++m_)
            #pragma unroll
            for (int n_ = 0; n_ < 4; ++n_)
                acc[m_][n_] = __builtin_amdgcn_mfma_f32_16x16x32_bf16(
                    af[m_], bfr[n_], acc[m_][n_], 0, 0, 0);
    }

    #pragma unroll
    for (int m_ = 0; m_ < 4; ++m_) {
        #pragma unroll
        for (int n_ = 0; n_ < 4; ++n_) {
            int c = nbase + wc * 64 + n_ * 16 + fr;
            #pragma unroll
            for (int j = 0; j < 4; ++j) {
                int mg = mbase + wr * 64 + m_ * 16 + hi * 4 + j;
                float v = acc[m_][n_][j];
                if (EPI == 0) {
                    ((float*)o0v)[(size_t)mg * 1024 + c] = v;
                } else {
                    int b = mg >> 11, s = mg & 2047;
                    int cc = c & 1023, h = cc >> 6, d = cc & 63;
                    unsigned short* dst = (c < 1024) ? (unsigned short*)o0v
                                        : (c < 2048) ? (unsigned short*)o1v
                                                     : (unsigned short*)o2v;
                    dst[(((size_t)b * HH + h) * SS + s) * DD + d] = f2bf(v);
                }
            }
        }
    }
}

// ------------------------------------------------------------------
// RoPE in-place on bf16 q,k; V lerp -> V^T bf16 [bh][d][s]
// ------------------------------------------------------------------
__global__ __launch_bounds__(256) void rope_lerp_kernel(
    unsigned short* __restrict__ q, unsigned short* __restrict__ k,
    const unsigned short* __restrict__ v0, const float* __restrict__ vres,
    const float* __restrict__ mix, unsigned short* __restrict__ vt)
{
    int st = blockIdx.x;
    int bh = blockIdx.y;
    int tid = threadIdx.x;
    int sl = tid >> 2;
    int dg = (tid & 3) * 16;
    int s = st * 64 + sl;
    size_t rowoff = ((size_t)bh * SS + s) * DD + dg;

    __shared__ unsigned short vtile[64][66];

    union { uint4 v[2]; unsigned short u[16]; } qa, ka, va;
    qa.v[0] = *(const uint4*)(q + rowoff);
    qa.v[1] = *(const uint4*)(q + rowoff + 8);
    ka.v[0] = *(const uint4*)(k + rowoff);
    ka.v[1] = *(const uint4*)(k + rowoff + 8);
    va.v[0] = *(const uint4*)(v0 + rowoff);
    va.v[1] = *(const uint4*)(v0 + rowoff + 8);
    float4 w[4];
    #pragma unroll
    for (int u = 0; u < 4; ++u) w[u] = *(const float4*)(vres + rowoff + 4 * u);
    float mx = mix[(size_t)bh * SS + s];

    #pragma unroll
    for (int u = 0; u < 8; ++u) {
        int d0 = dg + 2 * u;
        float inv_freq = powf(10000.f, -(float)d0 * (1.f / 64.f));
        float fr = (float)s * inv_freq;
        float red = fr - 6.2831853f * floorf(fr * 0.15915494f);
        float cs, sn;
        __sincosf(red, &sn, &cs);
        float x = bf2f(qa.u[2 * u]), y = bf2f(qa.u[2 * u + 1]);
        qa.u[2 * u]     = f2bf((x * cs - y * sn) * 0.125f);
        qa.u[2 * u + 1] = f2bf((y * cs + x * sn) * 0.125f);
        x = bf2f(ka.u[2 * u]); y = bf2f(ka.u[2 * u + 1]);
        ka.u[2 * u]     = f2bf(x * cs - y * sn);
        ka.u[2 * u + 1] = f2bf(y * cs + x * sn);
    }
    *(uint4*)(q + rowoff)     = qa.v[0];
    *(uint4*)(q + rowoff + 8) = qa.v[1];
    *(uint4*)(k + rowoff)     = ka.v[0];
    *(uint4*)(k + rowoff + 8) = ka.v[1];

    #pragma unroll
    for (int e = 0; e < 16; ++e) {
        float vv = bf2f(va.u[e]);
        float wr = ((const float*)w)[e];
        vtile[sl][dg + e] = f2bf(vv + mx * (wr - vv));
    }
    __syncthreads();

    int d = tid >> 2;
    int sseg = (tid & 3) * 16;
    union { uint4 v[2]; unsigned short u[16]; } ot;
    #pragma unroll
    for (int e = 0; e < 16; ++e) ot.u[e] = vtile[sseg + e][d];
    unsigned short* dst = vt + ((size_t)bh * DD + d) * SS + st * 64 + sseg;
    *(uint4*)dst = ot.v[0];
    *(uint4*)(dst + 8) = ot.v[1];
}

// ------------------------------------------------------------------
// MFMA flash attention, LDS-staged K/V tiles, XCD-swizzled 1D grid
// 1024 blocks (32 qt x 32 bh), 4 waves x 16 queries
// ------------------------------------------------------------------
__global__ __launch_bounds__(256) void attn_mfma(
    const unsigned short* __restrict__ qbh, const unsigned short* __restrict__ kbh,
    const unsigned short* __restrict__ vt, const int* __restrict__ epstart,
    const float* __restrict__ gate, unsigned short* __restrict__ ao)
{
    int orig = blockIdx.x;
    int swz  = (orig & 7) * 128 + (orig >> 3);   // bijective XCD swizzle (1024 % 8 == 0)
    int bh = swz >> 5, qt = swz & 31;
    int b = bh >> 4, h = bh & 15;
    int q0 = qt * 64;
    int tid = threadIdx.x;
    int wave = tid >> 6, lane = tid & 63;
    int lq = lane & 15, lg = lane >> 4;
    int i = q0 + wave * 16 + lq;

    __shared__ unsigned short Ks[4096];          // 64 rows(j) x 64 d, 16B-chunk XOR-swizzled
    __shared__ unsigned short Vs[4096];          // 64 rows(d) x 64 j, same swizzle
    alignas(16) __shared__ unsigned short P_lds[4][16][72];

    // staging: thread covers LDS 16B slot tid (rows 0-31) and 256+tid (rows 32-63);
    // global source chunk is XOR-picked so LDS[row][c] = global chunk (row, c^(row&7))
    int srow0 = tid >> 3, sch = tid & 7;
    int srow1 = srow0 + 32;
    int sc0 = ((sch ^ (srow0 & 7)) << 3);
    int sc1 = ((sch ^ (srow1 & 7)) << 3);
    const unsigned short* kS0 = kbh + ((size_t)bh * SS + srow0) * DD + sc0;
    const unsigned short* kS1 = kbh + ((size_t)bh * SS + srow1) * DD + sc1;
    const unsigned short* vS0 = vt + ((size_t)bh * DD + srow0) * SS + sc0;
    const unsigned short* vS1 = vt + ((size_t)bh * DD + srow1) * SS + sc1;
    unsigned short* kd0 = &Ks[tid * 8];
    unsigned short* kd1 = &Ks[2048 + tid * 8];
    unsigned short* vd0 = &Vs[tid * 8];
    unsigned short* vd1 = &Vs[2048 + tid * 8];

    // fragment read indices (same for Ks and Vs): row 16n+lq, chunks lg / lg+4
    int fidx[4];
    #pragma unroll
    for (int n = 0; n < 4; ++n) {
        int r = 16 * n + lq;
        fidx[n] = r * 64 + ((lg ^ (r & 7)) << 3);
    }

    // Q fragments (B-operand: col=q, K=d)
    const unsigned short* qrow = qbh + ((size_t)bh * SS + i) * DD + lg * 8;
    bf16x8 bq0 = *(const bf16x8*)qrow;
    bf16x8 bq1 = *(const bf16x8*)(qrow + 32);

    int jmin = i - WINDOW;
    int es = epstart[b * SS + i];
    if (es > jmin) jmin = es;
    float gi = gate[(size_t)bh * SS + i];

    float m = -1e30f, l = 0.f;
    f32x4 o[4];
    #pragma unroll
    for (int n = 0; n < 4; ++n) o[n] = (f32x4){0.f, 0.f, 0.f, 0.f};

    int t0 = (qt < 8) ? (8 - qt) : 0;
    for (int t = t0; t < 9; ++t) {
        int jbase = 64 * (qt - 8 + t);

        __syncthreads();                          // prev tile's LDS reads done
        async_cp16(kd0, kS0 + (size_t)jbase * DD);
        async_cp16(kd1, kS1 + (size_t)jbase * DD);
        async_cp16(vd0, vS0 + jbase);
        async_cp16(vd1, vS1 + jbase);
        __syncthreads();                          // staging complete

        // S^T = K @ Q
        f32x4 acc[4];
        #pragma unroll
        for (int n = 0; n < 4; ++n) acc[n] = (f32x4){0.f, 0.f, 0.f, 0.f};
        #pragma unroll
        for (int n = 0; n < 4; ++n) {
            bf16x8 kf0 = *(const bf16x8*)&Ks[fidx[n]];
            bf16x8 kf1 = *(const bf16x8*)&Ks[fidx[n] ^ 32];
            acc[n] = __builtin_amdgcn_mfma_f32_16x16x32_bf16(kf0, bq0, acc[n], 0, 0, 0);
            acc[n] = __builtin_amdgcn_mfma_f32_16x16x32_bf16(kf1, bq1, acc[n], 0, 0, 0);
        }

        // mask (window + episode via epstart)
        int jb = jbase + lg * 4;
        #pragma unroll
        for (int n = 0; n < 4; ++n)
            #pragma unroll
            for (int r = 0; r < 4; ++r) {
                int j = jb + 16 * n + r;
                if (j < jmin || j > i) acc[n][r] = -3e38f;
            }

        // online softmax (per-lane scalar m,l)
        float tm = -3e38f;
        #pragma unroll
        for (int n = 0; n < 4; ++n)
            tm = fmaxf(tm, fmaxf(fmaxf(acc[n][0], acc[n][1]), fmaxf(acc[n][2], acc[n][3])));
        tm = fmaxf(tm, __shfl_xor(tm, 16, 64));
        tm = fmaxf(tm, __shfl_xor(tm, 32, 64));
        float mnew = fmaxf(m, tm);
        float scale = __expf(m - mnew);
        float ts = 0.f;
        #pragma unroll
        for (int n = 0; n < 4; ++n)
            #pragma unroll
            for (int r = 0; r < 4; ++r) {
                float p = __expf(acc[n][r] - mnew);
                acc[n][r] = p;
                ts += p;
            }
        ts += __shfl_xor(ts, 16, 64);
        ts += __shfl_xor(ts, 32, 64);
        l = l * scale + ts;
        m = mnew;
        #pragma unroll
        for (int n = 0; n < 4; ++n) o[n] = o[n] * scale;

        // P -> per-wave LDS, then PV B-frags
        #pragma unroll
        for (int n = 0; n < 4; ++n) {
            ushort4 u;
            u.x = f2bf(acc[n][0]); u.y = f2bf(acc[n][1]);
            u.z = f2bf(acc[n][2]); u.w = f2bf(acc[n][3]);
            *(ushort4*)&P_lds[wave][lq][16 * n + lg * 4] = u;
        }
        bf16x8 bp0 = *(const bf16x8*)&P_lds[wave][lq][lg * 8];
        bf16x8 bp1 = *(const bf16x8*)&P_lds[wave][lq][32 + lg * 8];

        // O^T += V^T @ P^T
        #pragma unroll
        for (int n = 0; n < 4; ++n) {
            bf16x8 vf0 = *(const bf16x8*)&Vs[fidx[n]];
            bf16x8 vf1 = *(const bf16x8*)&Vs[fidx[n] ^ 32];
            o[n] = __builtin_amdgcn_mfma_f32_16x16x32_bf16(vf0, bp0, o[n], 0, 0, 0);
            o[n] = __builtin_amdgcn_mfma_f32_16x16x32_bf16(vf1, bp1, o[n], 0, 0, 0);
        }
    }

    float g = gi / l;
    #pragma unroll
    for (int n = 0; n < 4; ++n) {
        ushort4 u;
        u.x = f2bf(o[n][0] * g); u.y = f2bf(o[n][1] * g);
        u.z = f2bf(o[n][2] * g); u.w = f2bf(o[n][3] * g);
        *(ushort4*)(ao + (((size_t)b * SS + i) * HH + h) * DD + 16 * n + lg * 4) = u;
    }
}

// ------------------------------------------------------------------
extern "C" void kernel_launch(void* const* d_in, const int* in_sizes, int n_in,
                              void* d_out, int out_size, void* d_ws, size_t ws_size,
                              hipStream_t stream)
{
    const float* tokens = (const float*)d_in[0];
    const float* vres   = (const float*)d_in[1];
    const int*   ep     = (const int*)d_in[2];
    const float* Wq     = (const float*)d_in[3];
    const float* Wkv    = (const float*)d_in[4];
    const float* Wo     = (const float*)d_in[5];
    const float* Wg     = (const float*)d_in[6];
    const float* Wmix   = (const float*)d_in[7];
    float* out = (float*)d_out;

    char* wsb = (char*)d_ws;
    unsigned short* qbh  = (unsigned short*)(wsb + 0);         // 8 MB
    unsigned short* kbh  = (unsigned short*)(wsb + 8388608);   // 8 MB
    unsigned short* vb0  = (unsigned short*)(wsb + 16777216);  // 8 MB
    unsigned short* vtb  = (unsigned short*)(wsb + 25165824);  // 8 MB
    unsigned short* aob  = (unsigned short*)(wsb + 33554432);  // 8 MB
    unsigned short* tokA = (unsigned short*)(wsb + 41943040);  // 8 MB
    unsigned short* BtW  = (unsigned short*)(wsb + 50331648);  // 6 MB
    unsigned short* WotW = BtW;                                 // alias (after proj)
    float* gatep = (float*)(wsb + 56623104);                   // 256 KB
    float* mixp  = (float*)(wsb + 56885248);                   // 256 KB
    int*   epst  = (int*)(wsb + 57147392);                     // 16 KB
    unsigned short* wgmt = (unsigned short*)(wsb + 57163776);  // 64 KB

    cvt_bf16_kernel<<<2048, 256, 0, stream>>>(tokens, tokA, (BB * SS * DIMM) / 4);
    transpose_cvt_kernel<<<dim3(32, 32), dim3(32, 8), 0, stream>>>(Wq,  BtW,               1024, 1024);
    transpose_cvt_kernel<<<dim3(64, 32), dim3(32, 8), 0, stream>>>(Wkv, BtW + 1024 * 1024, 1024, 2048);
    build_wgmt_kernel<<<128, 256, 0, stream>>>(Wg, Wmix, wgmt);
    epstart_kernel<<<16, 256, 0, stream>>>(ep, epst);

    mixgate_mfma<<<128, 256, 0, stream>>>(tokA, wgmt, gatep, mixp);
    gemm_mfma<1><<<dim3(24, 32), 256, 0, stream>>>(tokA, BtW, qbh, kbh, vb0);
    rope_lerp_kernel<<<dim3(SS / 64, BB * HH), 256, 0, stream>>>(qbh, kbh, vb0, vres, mixp, vtb);
    attn_mfma<<<1024, 256, 0, stream>>>(qbh, kbh, vtb, epst, gatep, aob);

    transpose_cvt_kernel<<<dim3(32, 32), dim3(32, 8), 0, stream>>>(Wo, WotW, 1024, 1024);
    gemm_mfma<0><<<dim3(8, 32), 256, 0, stream>>>(aob, WotW, out, nullptr, nullptr);
}

// Round 7
// 128.020 us; speedup vs baseline: 17.1170x; 1.0317x over previous
//
#include <hip/hip_runtime.h>
#include <math.h>

#define BB 2
#define SS 2048
#define DIMM 1024
#define HH 16
#define DD 64
#define WINDOW 512

typedef __bf16 bf16x8 __attribute__((ext_vector_type(8)));
typedef float f32x4 __attribute__((ext_vector_type(4)));

__device__ __forceinline__ unsigned short f2bf(float f) {
    unsigned int u = __float_as_uint(f);
    u = (u + 0x7FFFu + ((u >> 16) & 1u)) >> 16;
    return (unsigned short)u;
}
__device__ __forceinline__ float bf2f(unsigned short u) {
    return __uint_as_float((unsigned int)u << 16);
}

__device__ __forceinline__ void async_cp16(unsigned short* lds_dst, const unsigned short* g_src) {
    __builtin_amdgcn_global_load_lds(
        (const __attribute__((address_space(1))) unsigned int*)g_src,
        (__attribute__((address_space(3))) unsigned int*)lds_dst, 16, 0, 0);
}

// ------------------------------------------------------------------
// fp32 -> bf16 flat convert (tokens)
// ------------------------------------------------------------------
__global__ __launch_bounds__(256) void cvt_bf16_kernel(
    const float* __restrict__ src, unsigned short* __restrict__ dst, int n4)
{
    for (int i = blockIdx.x * 256 + threadIdx.x; i < n4; i += gridDim.x * 256) {
        float4 v = ((const float4*)src)[i];
        ushort4 o;
        o.x = f2bf(v.x); o.y = f2bf(v.y); o.z = f2bf(v.z); o.w = f2bf(v.w);
        ((ushort4*)dst)[i] = o;
    }
}

// ------------------------------------------------------------------
// transpose + convert: src fp32 [R][C] -> dst bf16 [C][R]
// ------------------------------------------------------------------
__global__ __launch_bounds__(256) void transpose_cvt_kernel(
    const float* __restrict__ src, unsigned short* __restrict__ dst, int R, int C)
{
    __shared__ float t[32][33];
    int c0 = blockIdx.x * 32, r0 = blockIdx.y * 32;
    int tx = threadIdx.x, ty = threadIdx.y;
    #pragma unroll
    for (int u = 0; u < 4; ++u)
        t[ty + 8 * u][tx] = src[(size_t)(r0 + ty + 8 * u) * C + c0 + tx];
    __syncthreads();
    #pragma unroll
    for (int u = 0; u < 4; ++u)
        dst[(size_t)(c0 + ty + 8 * u) * R + r0 + tx] = f2bf(t[tx][ty + 8 * u]);
}

// ------------------------------------------------------------------
// pack [Wg|Wmix] (each [1024][16] fp32) -> N-major bf16 [32][1024]
// ------------------------------------------------------------------
__global__ __launch_bounds__(256) void build_wgmt_kernel(
    const float* __restrict__ Wg, const float* __restrict__ Wmix,
    unsigned short* __restrict__ dst)
{
    int idx = blockIdx.x * 256 + threadIdx.x;   // 0..32767
    int n = idx >> 10, k = idx & 1023;
    const float* src = (n < 16) ? Wg : Wmix;
    dst[idx] = f2bf(src[k * HH + (n & 15)]);
}

// ------------------------------------------------------------------
// mix & gate via MFMA: sigmoid(tokens_bf16 @ Wgm^T), N=32
// ------------------------------------------------------------------
__global__ __launch_bounds__(256) void mixgate_mfma(
    const unsigned short* __restrict__ A,      // [4096][1024] bf16
    const unsigned short* __restrict__ Bt,     // [32][1024] bf16
    float* __restrict__ gate, float* __restrict__ mix)
{
    int mbase = blockIdx.x * 32;
    int tid = threadIdx.x;
    int wave = tid >> 6, lane = tid & 63;
    int fr = lane & 15, hi = lane >> 4;
    int kw = wave * 256;

    __shared__ float red[4][32][32];

    f32x4 acc[2][2];
    #pragma unroll
    for (int m_ = 0; m_ < 2; ++m_)
        #pragma unroll
        for (int n_ = 0; n_ < 2; ++n_)
            acc[m_][n_] = (f32x4){0.f, 0.f, 0.f, 0.f};

    const unsigned short* a0 = A + (size_t)(mbase + fr) * 1024 + kw + hi * 8;
    const unsigned short* a1 = A + (size_t)(mbase + 16 + fr) * 1024 + kw + hi * 8;
    const unsigned short* b0 = Bt + (size_t)fr * 1024 + kw + hi * 8;
    const unsigned short* b1 = Bt + (size_t)(16 + fr) * 1024 + kw + hi * 8;

    #pragma unroll 2
    for (int k = 0; k < 256; k += 32) {
        bf16x8 af0 = *(const bf16x8*)(a0 + k);
        bf16x8 af1 = *(const bf16x8*)(a1 + k);
        bf16x8 bf0 = *(const bf16x8*)(b0 + k);
        bf16x8 bf1 = *(const bf16x8*)(b1 + k);
        acc[0][0] = __builtin_amdgcn_mfma_f32_16x16x32_bf16(af0, bf0, acc[0][0], 0, 0, 0);
        acc[0][1] = __builtin_amdgcn_mfma_f32_16x16x32_bf16(af0, bf1, acc[0][1], 0, 0, 0);
        acc[1][0] = __builtin_amdgcn_mfma_f32_16x16x32_bf16(af1, bf0, acc[1][0], 0, 0, 0);
        acc[1][1] = __builtin_amdgcn_mfma_f32_16x16x32_bf16(af1, bf1, acc[1][1], 0, 0, 0);
    }

    #pragma unroll
    for (int m_ = 0; m_ < 2; ++m_)
        #pragma unroll
        for (int n_ = 0; n_ < 2; ++n_)
            #pragma unroll
            for (int j = 0; j < 4; ++j)
                red[wave][m_ * 16 + hi * 4 + j][n_ * 16 + fr] = acc[m_][n_][j];
    __syncthreads();

    #pragma unroll
    for (int e = 0; e < 4; ++e) {
        int idx = (tid << 2) | e;          // 0..1023
        int r = idx >> 5, c = idx & 31;
        float s4 = red[0][r][c] + red[1][r][c] + red[2][r][c] + red[3][r][c];
        float sg = 1.f / (1.f + __expf(-s4));
        int mg = mbase + r;
        int b = mg >> 11, s = mg & 2047;
        int h = c & 15;
        float* dst = (c < 16) ? gate : mix;
        dst[((size_t)b * HH + h) * SS + s] = sg;
    }
}

// ------------------------------------------------------------------
// episode start: epstart[b][i] = first index of i's episode (sorted ids)
// ------------------------------------------------------------------
__global__ __launch_bounds__(256) void epstart_kernel(
    const int* __restrict__ ep, int* __restrict__ epstart)
{
    int idx = blockIdx.x * 256 + threadIdx.x;   // b*S + i
    int b = idx >> 11, i = idx & 2047;
    const int* e = ep + b * SS;
    int v = e[i];
    int lo = 0, hi = i;
    while (lo < hi) {
        int mid = (lo + hi) >> 1;
        if (e[mid] == v) hi = mid; else lo = mid + 1;
    }
    epstart[idx] = lo;
}

// ------------------------------------------------------------------
// bf16 MFMA GEMM, prefetch double-buffered LDS (1 barrier / K-step).
// A [M][1024] bf16 row-major, Bt [N][1024] bf16 (N-major).
// BN = 128: 4 waves as 2x2, each 64x64 (4x4 frags)
// BN =  64: 4 waves as 2x2, each 64x32 (4x2 frags)
// EPI=0: C fp32 [M][1024]; EPI=1: scatter bf16 q/k/v (B,H,S,D)
// ------------------------------------------------------------------
template<int EPI, int BN>
__global__ __launch_bounds__(256) void gemm_mfma(
    const unsigned short* __restrict__ A, const unsigned short* __restrict__ Bt,
    void* __restrict__ o0v, void* __restrict__ o1v, void* __restrict__ o2v)
{
    const int K = 1024;
    constexpr int NFR = BN / 32;               // N frags per wave
    int nbase = blockIdx.x * BN;
    int mbase = blockIdx.y * 128;
    int tid = threadIdx.x;
    int lane = tid & 63;
    int wave = tid >> 6;
    int wr = wave >> 1, wc = wave & 1;
    int fr = lane & 15, hi = lane >> 4;

    __shared__ unsigned short As[2][128 * 32];
    __shared__ unsigned short Bs[2][BN * 32];

    // staging geometry: thread t covers 16B slot t (rows 0-63), slot 256+t (rows 64-127)
    int srow = tid >> 2;
    int sp   = tid & 3;
    int scol = (sp ^ ((srow >> 1) & 3)) * 8;   // same swizzle for row and row+64
    const unsigned short* agp0 = A  + (size_t)(mbase + srow) * K + scol;
    const unsigned short* agp1 = A  + (size_t)(mbase + srow + 64) * K + scol;
    const unsigned short* bgp0 = Bt + (size_t)(nbase + srow) * K + scol;
    const unsigned short* bgp1 = (BN == 128)
        ? Bt + (size_t)(nbase + srow + 64) * K + scol : bgp0;

    f32x4 acc[4][NFR];
    #pragma unroll
    for (int m_ = 0; m_ < 4; ++m_)
        #pragma unroll
        for (int n_ = 0; n_ < NFR; ++n_)
            acc[m_][n_] = (f32x4){0.f, 0.f, 0.f, 0.f};

    int aidx[4], bidx[NFR];
    #pragma unroll
    for (int m_ = 0; m_ < 4; ++m_) {
        int row = wr * 64 + m_ * 16 + fr;
        aidx[m_] = row * 32 + (hi ^ ((row >> 1) & 3)) * 8;
    }
    #pragma unroll
    for (int n_ = 0; n_ < NFR; ++n_) {
        int row = wc * (BN / 2) + n_ * 16 + fr;
        bidx[n_] = row * 32 + (hi ^ ((row >> 1) & 3)) * 8;
    }

    auto stage = [&](int buf, int k0) {
        async_cp16(&As[buf][tid * 8], agp0 + k0);
        async_cp16(&As[buf][2048 + tid * 8], agp1 + k0);
        async_cp16(&Bs[buf][tid * 8], bgp0 + k0);
        if constexpr (BN == 128)
            async_cp16(&Bs[buf][2048 + tid * 8], bgp1 + k0);
    };

    stage(0, 0);                                 // prologue
    for (int k0 = 0; k0 < K; k0 += 32) {
        int cur = (k0 >> 5) & 1;
        __syncthreads();                         // buf[cur] staged (vmcnt drained); prev reads done
        if (k0 + 32 < K) stage(cur ^ 1, k0 + 32);// prefetch flies under this tile's MFMAs

        bf16x8 af[4], bfr[NFR];
        #pragma unroll
        for (int m_ = 0; m_ < 4; ++m_) af[m_] = *(const bf16x8*)&As[cur][aidx[m_]];
        #pragma unroll
        for (int n_ = 0; n_ < NFR; ++n_) bfr[n_] = *(const bf16x8*)&Bs[cur][bidx[n_]];
        #pragma unroll
        for (int m_ = 0; m_ < 4; ++m_)
            #pragma unroll
            for (int n_ = 0; n_ < NFR; ++n_)
                acc[m_][n_] = __builtin_amdgcn_mfma_f32_16x16x32_bf16(
                    af[m_], bfr[n_], acc[m_][n_], 0, 0, 0);
    }

    #pragma unroll
    for (int m_ = 0; m_ < 4; ++m_) {
        #pragma unroll
        for (int n_ = 0; n_ < NFR; ++n_) {
            int c = nbase + wc * (BN / 2) + n_ * 16 + fr;
            #pragma unroll
            for (int j = 0; j < 4; ++j) {
                int mg = mbase + wr * 64 + m_ * 16 + hi * 4 + j;
                float v = acc[m_][n_][j];
                if (EPI == 0) {
                    ((float*)o0v)[(size_t)mg * 1024 + c] = v;
                } else {
                    int b = mg >> 11, s = mg & 2047;
                    int cc = c & 1023, h = cc >> 6, d = cc & 63;
                    unsigned short* dst = (c < 1024) ? (unsigned short*)o0v
                                        : (c < 2048) ? (unsigned short*)o1v
                                                     : (unsigned short*)o2v;
                    dst[(((size_t)b * HH + h) * SS + s) * DD + d] = f2bf(v);
                }
            }
        }
    }
}

// ------------------------------------------------------------------
// RoPE in-place on bf16 q,k; V lerp -> V^T bf16 [bh][d][s]
// ------------------------------------------------------------------
__global__ __launch_bounds__(256) void rope_lerp_kernel(
    unsigned short* __restrict__ q, unsigned short* __restrict__ k,
    const unsigned short* __restrict__ v0, const float* __restrict__ vres,
    const float* __restrict__ mix, unsigned short* __restrict__ vt)
{
    int st = blockIdx.x;
    int bh = blockIdx.y;
    int tid = threadIdx.x;
    int sl = tid >> 2;
    int dg = (tid & 3) * 16;
    int s = st * 64 + sl;
    size_t rowoff = ((size_t)bh * SS + s) * DD + dg;

    __shared__ unsigned short vtile[64][66];

    union { uint4 v[2]; unsigned short u[16]; } qa, ka, va;
    qa.v[0] = *(const uint4*)(q + rowoff);
    qa.v[1] = *(const uint4*)(q + rowoff + 8);
    ka.v[0] = *(const uint4*)(k + rowoff);
    ka.v[1] = *(const uint4*)(k + rowoff + 8);
    va.v[0] = *(const uint4*)(v0 + rowoff);
    va.v[1] = *(const uint4*)(v0 + rowoff + 8);
    float4 w[4];
    #pragma unroll
    for (int u = 0; u < 4; ++u) w[u] = *(const float4*)(vres + rowoff + 4 * u);
    float mx = mix[(size_t)bh * SS + s];

    #pragma unroll
    for (int u = 0; u < 8; ++u) {
        int d0 = dg + 2 * u;
        float inv_freq = powf(10000.f, -(float)d0 * (1.f / 64.f));
        float fr = (float)s * inv_freq;
        float red = fr - 6.2831853f * floorf(fr * 0.15915494f);
        float cs, sn;
        __sincosf(red, &sn, &cs);
        float x = bf2f(qa.u[2 * u]), y = bf2f(qa.u[2 * u + 1]);
        qa.u[2 * u]     = f2bf((x * cs - y * sn) * 0.125f);
        qa.u[2 * u + 1] = f2bf((y * cs + x * sn) * 0.125f);
        x = bf2f(ka.u[2 * u]); y = bf2f(ka.u[2 * u + 1]);
        ka.u[2 * u]     = f2bf(x * cs - y * sn);
        ka.u[2 * u + 1] = f2bf(y * cs + x * sn);
    }
    *(uint4*)(q + rowoff)     = qa.v[0];
    *(uint4*)(q + rowoff + 8) = qa.v[1];
    *(uint4*)(k + rowoff)     = ka.v[0];
    *(uint4*)(k + rowoff + 8) = ka.v[1];

    #pragma unroll
    for (int e = 0; e < 16; ++e) {
        float vv = bf2f(va.u[e]);
        float wr = ((const float*)w)[e];
        vtile[sl][dg + e] = f2bf(vv + mx * (wr - vv));
    }
    __syncthreads();

    int d = tid >> 2;
    int sseg = (tid & 3) * 16;
    union { uint4 v[2]; unsigned short u[16]; } ot;
    #pragma unroll
    for (int e = 0; e < 16; ++e) ot.u[e] = vtile[sseg + e][d];
    unsigned short* dst = vt + ((size_t)bh * DD + d) * SS + st * 64 + sseg;
    *(uint4*)dst = ot.v[0];
    *(uint4*)(dst + 8) = ot.v[1];
}

// ------------------------------------------------------------------
// MFMA flash attention, LDS-staged K/V tiles, XCD-swizzled 1D grid
// ------------------------------------------------------------------
__global__ __launch_bounds__(256) void attn_mfma(
    const unsigned short* __restrict__ qbh, const unsigned short* __restrict__ kbh,
    const unsigned short* __restrict__ vt, const int* __restrict__ epstart,
    const float* __restrict__ gate, unsigned short* __restrict__ ao)
{
    int orig = blockIdx.x;
    int swz  = (orig & 7) * 128 + (orig >> 3);   // bijective XCD swizzle (1024 % 8 == 0)
    int bh = swz >> 5, qt = swz & 31;
    int b = bh >> 4, h = bh & 15;
    int q0 = qt * 64;
    int tid = threadIdx.x;
    int wave = tid >> 6, lane = tid & 63;
    int lq = lane & 15, lg = lane >> 4;
    int i = q0 + wave * 16 + lq;

    __shared__ unsigned short Ks[4096];
    __shared__ unsigned short Vs[4096];
    alignas(16) __shared__ unsigned short P_lds[4][16][72];

    int srow0 = tid >> 3, sch = tid & 7;
    int srow1 = srow0 + 32;
    int sc0 = ((sch ^ (srow0 & 7)) << 3);
    int sc1 = ((sch ^ (srow1 & 7)) << 3);
    const unsigned short* kS0 = kbh + ((size_t)bh * SS + srow0) * DD + sc0;
    const unsigned short* kS1 = kbh + ((size_t)bh * SS + srow1) * DD + sc1;
    const unsigned short* vS0 = vt + ((size_t)bh * DD + srow0) * SS + sc0;
    const unsigned short* vS1 = vt + ((size_t)bh * DD + srow1) * SS + sc1;
    unsigned short* kd0 = &Ks[tid * 8];
    unsigned short* kd1 = &Ks[2048 + tid * 8];
    unsigned short* vd0 = &Vs[tid * 8];
    unsigned short* vd1 = &Vs[2048 + tid * 8];

    int fidx[4];
    #pragma unroll
    for (int n = 0; n < 4; ++n) {
        int r = 16 * n + lq;
        fidx[n] = r * 64 + ((lg ^ (r & 7)) << 3);
    }

    const unsigned short* qrow = qbh + ((size_t)bh * SS + i) * DD + lg * 8;
    bf16x8 bq0 = *(const bf16x8*)qrow;
    bf16x8 bq1 = *(const bf16x8*)(qrow + 32);

    int jmin = i - WINDOW;
    int es = epstart[b * SS + i];
    if (es > jmin) jmin = es;
    float gi = gate[(size_t)bh * SS + i];

    float m = -1e30f, l = 0.f;
    f32x4 o[4];
    #pragma unroll
    for (int n = 0; n < 4; ++n) o[n] = (f32x4){0.f, 0.f, 0.f, 0.f};

    int t0 = (qt < 8) ? (8 - qt) : 0;
    for (int t = t0; t < 9; ++t) {
        int jbase = 64 * (qt - 8 + t);

        __syncthreads();
        async_cp16(kd0, kS0 + (size_t)jbase * DD);
        async_cp16(kd1, kS1 + (size_t)jbase * DD);
        async_cp16(vd0, vS0 + jbase);
        async_cp16(vd1, vS1 + jbase);
        __syncthreads();

        f32x4 acc[4];
        #pragma unroll
        for (int n = 0; n < 4; ++n) acc[n] = (f32x4){0.f, 0.f, 0.f, 0.f};
        #pragma unroll
        for (int n = 0; n < 4; ++n) {
            bf16x8 kf0 = *(const bf16x8*)&Ks[fidx[n]];
            bf16x8 kf1 = *(const bf16x8*)&Ks[fidx[n] ^ 32];
            acc[n] = __builtin_amdgcn_mfma_f32_16x16x32_bf16(kf0, bq0, acc[n], 0, 0, 0);
            acc[n] = __builtin_amdgcn_mfma_f32_16x16x32_bf16(kf1, bq1, acc[n], 0, 0, 0);
        }

        int jb = jbase + lg * 4;
        #pragma unroll
        for (int n = 0; n < 4; ++n)
            #pragma unroll
            for (int r = 0; r < 4; ++r) {
                int j = jb + 16 * n + r;
                if (j < jmin || j > i) acc[n][r] = -3e38f;
            }

        float tm = -3e38f;
        #pragma unroll
        for (int n = 0; n < 4; ++n)
            tm = fmaxf(tm, fmaxf(fmaxf(acc[n][0], acc[n][1]), fmaxf(acc[n][2], acc[n][3])));
        tm = fmaxf(tm, __shfl_xor(tm, 16, 64));
        tm = fmaxf(tm, __shfl_xor(tm, 32, 64));
        float mnew = fmaxf(m, tm);
        float scale = __expf(m - mnew);
        float ts = 0.f;
        #pragma unroll
        for (int n = 0; n < 4; ++n)
            #pragma unroll
            for (int r = 0; r < 4; ++r) {
                float p = __expf(acc[n][r] - mnew);
                acc[n][r] = p;
                ts += p;
            }
        ts += __shfl_xor(ts, 16, 64);
        ts += __shfl_xor(ts, 32, 64);
        l = l * scale + ts;
        m = mnew;
        #pragma unroll
        for (int n = 0; n < 4; ++n) o[n] = o[n] * scale;

        #pragma unroll
        for (int n = 0; n < 4; ++n) {
            ushort4 u;
            u.x = f2bf(acc[n][0]); u.y = f2bf(acc[n][1]);
            u.z = f2bf(acc[n][2]); u.w = f2bf(acc[n][3]);
            *(ushort4*)&P_lds[wave][lq][16 * n + lg * 4] = u;
        }
        bf16x8 bp0 = *(const bf16x8*)&P_lds[wave][lq][lg * 8];
        bf16x8 bp1 = *(const bf16x8*)&P_lds[wave][lq][32 + lg * 8];

        #pragma unroll
        for (int n = 0; n < 4; ++n) {
            bf16x8 vf0 = *(const bf16x8*)&Vs[fidx[n]];
            bf16x8 vf1 = *(const bf16x8*)&Vs[fidx[n] ^ 32];
            o[n] = __builtin_amdgcn_mfma_f32_16x16x32_bf16(vf0, bp0, o[n], 0, 0, 0);
            o[n] = __builtin_amdgcn_mfma_f32_16x16x32_bf16(vf1, bp1, o[n], 0, 0, 0);
        }
    }

    float g = gi / l;
    #pragma unroll
    for (int n = 0; n < 4; ++n) {
        ushort4 u;
        u.x = f2bf(o[n][0] * g); u.y = f2bf(o[n][1] * g);
        u.z = f2bf(o[n][2] * g); u.w = f2bf(o[n][3] * g);
        *(ushort4*)(ao + (((size_t)b * SS + i) * HH + h) * DD + 16 * n + lg * 4) = u;
    }
}

// ------------------------------------------------------------------
extern "C" void kernel_launch(void* const* d_in, const int* in_sizes, int n_in,
                              void* d_out, int out_size, void* d_ws, size_t ws_size,
                              hipStream_t stream)
{
    const float* tokens = (const float*)d_in[0];
    const float* vres   = (const float*)d_in[1];
    const int*   ep     = (const int*)d_in[2];
    const float* Wq     = (const float*)d_in[3];
    const float* Wkv    = (const float*)d_in[4];
    const float* Wo     = (const float*)d_in[5];
    const float* Wg     = (const float*)d_in[6];
    const float* Wmix   = (const float*)d_in[7];
    float* out = (float*)d_out;

    char* wsb = (char*)d_ws;
    unsigned short* qbh  = (unsigned short*)(wsb + 0);         // 8 MB
    unsigned short* kbh  = (unsigned short*)(wsb + 8388608);   // 8 MB
    unsigned short* vb0  = (unsigned short*)(wsb + 16777216);  // 8 MB
    unsigned short* vtb  = (unsigned short*)(wsb + 25165824);  // 8 MB
    unsigned short* aob  = (unsigned short*)(wsb + 33554432);  // 8 MB
    unsigned short* tokA = (unsigned short*)(wsb + 41943040);  // 8 MB
    unsigned short* BtW  = (unsigned short*)(wsb + 50331648);  // 6 MB
    unsigned short* WotW = BtW;                                 // alias (after proj)
    float* gatep = (float*)(wsb + 56623104);                   // 256 KB
    float* mixp  = (float*)(wsb + 56885248);                   // 256 KB
    int*   epst  = (int*)(wsb + 57147392);                     // 16 KB
    unsigned short* wgmt = (unsigned short*)(wsb + 57163776);  // 64 KB

    cvt_bf16_kernel<<<2048, 256, 0, stream>>>(tokens, tokA, (BB * SS * DIMM) / 4);
    transpose_cvt_kernel<<<dim3(32, 32), dim3(32, 8), 0, stream>>>(Wq,  BtW,               1024, 1024);
    transpose_cvt_kernel<<<dim3(64, 32), dim3(32, 8), 0, stream>>>(Wkv, BtW + 1024 * 1024, 1024, 2048);
    build_wgmt_kernel<<<128, 256, 0, stream>>>(Wg, Wmix, wgmt);
    epstart_kernel<<<16, 256, 0, stream>>>(ep, epst);

    mixgate_mfma<<<128, 256, 0, stream>>>(tokA, wgmt, gatep, mixp);
    gemm_mfma<1, 128><<<dim3(24, 32), 256, 0, stream>>>(tokA, BtW, qbh, kbh, vb0);
    rope_lerp_kernel<<<dim3(SS / 64, BB * HH), 256, 0, stream>>>(qbh, kbh, vb0, vres, mixp, vtb);
    attn_mfma<<<1024, 256, 0, stream>>>(qbh, kbh, vtb, epst, gatep, aob);

    transpose_cvt_kernel<<<dim3(32, 32), dim3(32, 8), 0, stream>>>(Wo, WotW, 1024, 1024);
    gemm_mfma<0, 64><<<dim3(16, 32), 256, 0, stream>>>(aob, WotW, out, nullptr, nullptr);
}